// Round 2
// baseline (4419.946 us; speedup 1.0000x reference)
//
#include <hip/hip_runtime.h>
#include <hip/hip_bf16.h>

typedef __hip_bfloat16 bf16;

#define BB 4
#define NN 2048
#define CCH 128
#define DDM 128
#define KNB 16
#define HHD 64
#define AAD 512
#define PP (BB*NN)

__device__ __forceinline__ float b2f(bf16 x) { return __bfloat162float(x); }

// Adaptive load: raw harness tensor may be fp32 or bf16; flag selects.
__device__ __forceinline__ float ldany(const void* p, size_t i, int f32) {
  return f32 ? ((const float*)p)[i] : __bfloat162float(((const bf16*)p)[i]);
}

struct PtrArr { const void* p[36]; int n[36]; };

// ---------- dtype sniffer: one block per tensor ----------
// Interpret first <=4096 elements as bf16; true-bf16 data is ~99.9% magnitude-
// plausible, fp32 bytes read as bf16 are only ~56% (low halves have random
// exponents). flags[t]=1 means the tensor is fp32.
__global__ __launch_bounds__(256) void sniff_kern(PtrArr pa, int* __restrict__ flags) {
  int t = blockIdx.x;
  const bf16* x = (const bf16*)pa.p[t];
  int n = pa.n[t]; if (n > 4096) n = 4096;
  __shared__ int cnt;
  if (threadIdx.x == 0) cnt = 0;
  __syncthreads();
  int c = 0;
  for (int i = threadIdx.x; i < n; i += 256) {
    float v = fabsf(__bfloat162float(x[i]));
    if (v == 0.f || (v >= 1e-6f && v <= 1024.f)) c++;
  }
  atomicAdd(&cnt, c);
  __syncthreads();
  if (threadIdx.x == 0) flags[t] = (cnt >= (n * 7) / 8) ? 0 : 1;
}

// ---------- transpose (B,C,N) raw -> token-major (P, ldd) bf16, at column offset ----------
__global__ __launch_bounds__(256) void tr_in_kern(const void* __restrict__ src,
                                                  const int* __restrict__ flags, int fIdx,
                                                  bf16* __restrict__ dst,
                                                  int C, int ldd, int coff) {
  __shared__ float tile[64][65];
  const int f32 = flags[fIdx];
  int b = blockIdx.z, n0 = blockIdx.x * 64, c0 = blockIdx.y * 64;
  int tx = threadIdx.x & 63, ty = threadIdx.x >> 6;
  for (int r = ty; r < 64; r += 4)
    tile[r][tx] = ldany(src, (size_t)(b * C + c0 + r) * NN + n0 + tx, f32);
  __syncthreads();
  for (int r = ty; r < 64; r += 4)
    dst[(size_t)(b * NN + n0 + r) * ldd + coff + c0 + tx] = __float2bfloat16(tile[tx][r]);
}

// ---------- coords (B,dd,N) raw -> (P,4) fp32, zero-padded ----------
__global__ __launch_bounds__(256) void tr_coords_kern(const void* __restrict__ src,
                                                      const int* __restrict__ flags, int fIdx,
                                                      float* __restrict__ dst, int dd) {
  const int f32 = flags[fIdx];
  int i = blockIdx.x * 256 + threadIdx.x;
  if (i >= PP * 4) return;
  int p = i >> 2, j = i & 3;
  int b = p >> 11, n = p & (NN - 1);
  dst[i] = (j < dd) ? ldany(src, (size_t)(b * dd + j) * NN + n, f32) : 0.f;
}

// ---------- token-major linear: out[p][o] = act(W[o][:] . X[p][:] + bias[o] (+ add[p][o])) ----------
__global__ __launch_bounds__(256) void linear_kern(
    const bf16* __restrict__ X, int ldx, int Cin, int cinLog,
    const void* __restrict__ W, const void* __restrict__ bias,
    const int* __restrict__ flags, int wIdx, int bIdx,
    const bf16* __restrict__ add, bf16* __restrict__ out, int ldout, int relu) {
  __shared__ __attribute__((aligned(16))) float xt[16 * 256];
  __shared__ __attribute__((aligned(16))) float wbuf[64 * 132];
  const int wf = flags[wIdx], bfl = flags[bIdx];
  int tid = threadIdx.x;
  int p0 = blockIdx.x * 16, o0 = blockIdx.y * 64;
  for (int i = tid; i < 16 * Cin; i += 256) {
    int pl = i >> cinLog, c = i & (Cin - 1);
    xt[i] = b2f(X[(size_t)(p0 + pl) * ldx + c]);
  }
  int o = tid & 63, pg = tid >> 6;
  float bv = ldany(bias, o0 + o, bfl);
  float acc[4] = {bv, bv, bv, bv};
  for (int ch = 0; ch < Cin; ch += 128) {
    __syncthreads();  // xt ready / previous wbuf use done
    for (int i = tid; i < 64 * 128; i += 256) {
      int r = i >> 7, c = i & 127;
      wbuf[r * 132 + c] = ldany(W, (size_t)(o0 + r) * Cin + ch + c, wf);
    }
    __syncthreads();
    for (int c = 0; c < 128; c += 4) {
      float4 w = *(const float4*)&wbuf[o * 132 + c];
#pragma unroll
      for (int j = 0; j < 4; ++j) {
        const float4 xv = *(const float4*)&xt[((pg + 4 * j) << cinLog) + ch + c];
        acc[j] += w.x * xv.x + w.y * xv.y + w.z * xv.z + w.w * xv.w;
      }
    }
  }
#pragma unroll
  for (int j = 0; j < 4; ++j) {
    int p = p0 + pg + 4 * j;
    float v = acc[j];
    if (add) v += b2f(add[(size_t)p * 128 + o0 + o]);
    if (relu) v = fmaxf(v, 0.f);
    out[(size_t)p * ldout + o0 + o] = __float2bfloat16(v);
  }
}

// ---------- kNN (stable argsort semantics) from fp32 (P,4) coords ----------
__global__ __launch_bounds__(256) void knn_kern(const float* __restrict__ coordsT,
                                                int* __restrict__ idxout) {
  __shared__ __attribute__((aligned(16))) float4 cds[NN];
  __shared__ float d2s[NN];
  __shared__ unsigned long long red[4];
  int p = blockIdx.x, b = p >> 11, n = p & (NN - 1);
  int tid = threadIdx.x;
  for (int j = tid; j < NN; j += 256)
    cds[j] = *(const float4*)&coordsT[((size_t)(b << 11) + j) * 4];
  __syncthreads();
  float4 cc = cds[n];
  float sqi = __fadd_rn(__fadd_rn(__fmul_rn(cc.x, cc.x), __fmul_rn(cc.y, cc.y)),
                        __fmul_rn(cc.z, cc.z));
  for (int j = tid; j < NN; j += 256) {
    float4 q = cds[j];
    float sqj = __fadd_rn(__fadd_rn(__fmul_rn(q.x, q.x), __fmul_rn(q.y, q.y)),
                          __fmul_rn(q.z, q.z));
    float dt  = __fadd_rn(__fadd_rn(__fmul_rn(cc.x, q.x), __fmul_rn(cc.y, q.y)),
                          __fmul_rn(cc.z, q.z));
    d2s[j] = __fsub_rn(__fadd_rn(sqi, sqj), __fmul_rn(2.f, dt));
  }
  __syncthreads();
  for (int t = 0; t < KNB; ++t) {
    unsigned long long best = ~0ull;
    for (int j = tid; j < NN; j += 256) {
      unsigned u = __float_as_uint(d2s[j]);
      u = (u & 0x80000000u) ? ~u : (u | 0x80000000u);  // sortable ascending
      unsigned long long key = ((unsigned long long)u << 32) | (unsigned)j;
      best = best < key ? best : key;
    }
#pragma unroll
    for (int off = 32; off > 0; off >>= 1) {
      unsigned long long o2 = __shfl_down(best, off);
      best = best < o2 ? best : o2;
    }
    if ((tid & 63) == 0) red[tid >> 6] = best;
    __syncthreads();
    if (tid == 0) {
      unsigned long long m = red[0];
      for (int w = 1; w < 4; ++w) m = m < red[w] ? m : red[w];
      int j = (int)(m & 0xffffffffu);
      idxout[(size_t)p * KNB + t] = j;
      d2s[j] = __uint_as_float(0x7f800000u);  // +inf
    }
    __syncthreads();
  }
}

// ---------- fused kNN attention block: one workgroup per point ----------
__global__ __launch_bounds__(256) void attn_kern(
    const bf16* __restrict__ centerT, const bf16* __restrict__ gatherT,
    const float* __restrict__ coordsT, const bf16* __restrict__ vfeatT,
    const int* __restrict__ idx, int dd,
    const void* __restrict__ cw1, const void* __restrict__ cb1,
    const void* __restrict__ cw2, const void* __restrict__ cb2,
    const void* __restrict__ aw1, const void* __restrict__ ab1,
    const void* __restrict__ aw2, const void* __restrict__ ab2,
    const int* __restrict__ flags, int cIdx, int aIdx,
    bf16* __restrict__ aggT) {
  __shared__ __attribute__((aligned(16))) float xs[16 * 128];   // kq_rel + emb
  __shared__ __attribute__((aligned(16))) bf16 embs[16 * 128];  // emb for aggregation
  __shared__ __attribute__((aligned(16))) float sld[128 * 17];  // logits
  __shared__ __attribute__((aligned(16))) float hc[16 * 68];    // hidden chunk
  __shared__ __attribute__((aligned(16))) float wb[128 * 68];   // weight stage
  __shared__ int nidx[16];
  __shared__ float ctr[4], nbr[16 * 4];
  __shared__ float cfe[128], vfe[128];
  const int fcw1 = flags[cIdx], fcb1 = flags[cIdx + 1];
  const int fcw2 = flags[cIdx + 2], fcb2 = flags[cIdx + 3];
  const int faw1 = flags[aIdx], fab1 = flags[aIdx + 1];
  const int faw2 = flags[aIdx + 2], fab2 = flags[aIdx + 3];
  int p = blockIdx.x, b = p >> 11;
  int tid = threadIdx.x;
  if (tid < 16) nidx[tid] = (b << 11) + idx[(size_t)p * KNB + tid];
  if (tid >= 32 && tid < 36) ctr[tid - 32] = coordsT[(size_t)p * 4 + (tid - 32)];
  if (tid >= 64 && tid < 192) {
    cfe[tid - 64] = b2f(centerT[(size_t)p * 128 + (tid - 64)]);
    vfe[tid - 64] = b2f(vfeatT[(size_t)p * 128 + (tid - 64)]);
  }
  __syncthreads();
  if (tid < 64) nbr[tid] = coordsT[(size_t)nidx[tid >> 2] * 4 + (tid & 3)];
  for (int i = tid; i < 16 * 128; i += 256) {
    int kk = i >> 7, d = i & 127;
    xs[i] = cfe[d] - b2f(gatherT[(size_t)nidx[kk] * 128 + d]);
  }
  __syncthreads();
  // coord-emb hidden: (16,64) = relu(cw1 @ rel + cb1)
  for (int i = tid; i < 16 * 64; i += 256) {
    int kk = i >> 6, h = i & 63;
    float a = ldany(cb1, h, fcb1);
    for (int j = 0; j < dd; ++j)
      a += ldany(cw1, h * dd + j, fcw1) * (ctr[j] - nbr[kk * 4 + j]);
    hc[kk * 68 + h] = fmaxf(a, 0.f);
  }
  // stage cw2 (128x64) at ld 65
  for (int i = tid; i < 128 * 64; i += 256) {
    int d = i >> 6, h = i & 63;
    wb[d * 65 + h] = ldany(cw2, i, fcw2);
  }
  __syncthreads();
  // emb = cw2 @ hidden + cb2 ; xs += emb
  for (int i = tid; i < 16 * 128; i += 256) {
    int kk = i >> 7, d = i & 127;
    float a = ldany(cb2, d, fcb2);
    const float* wr = &wb[d * 65];
    const float* hr = &hc[kk * 68];
    for (int h = 0; h < 64; ++h) a += wr[h] * hr[h];
    embs[i] = __float2bfloat16(a);
    xs[i] += a;
  }
  // big MLP 128 -> 512 -> 128 in hidden chunks of 64, logits accumulated in regs
  int d = tid & 127, kg = tid >> 7;      // role C mapping
  float accs[8];
  float sbias = ldany(ab2, d, fab2);
#pragma unroll
  for (int j = 0; j < 8; ++j) accs[j] = sbias;
  int o = tid & 63, pg = tid >> 6;       // role B mapping
  for (int ac = 0; ac < 8; ++ac) {
    __syncthreads();
    for (int i = tid; i < 64 * 128; i += 256) {
      int r = i >> 7, c = i & 127;
      wb[r * 132 + c] = ldany(aw1, (size_t)(ac * 64 + r) * 128 + c, faw1);
    }
    __syncthreads();
    {
      float a0 = ldany(ab1, ac * 64 + o, fab1);
      float acc4[4] = {a0, a0, a0, a0};
      for (int c = 0; c < 128; c += 4) {
        float4 w = *(const float4*)&wb[o * 132 + c];
#pragma unroll
        for (int j = 0; j < 4; ++j) {
          const float4 xv = *(const float4*)&xs[(pg + 4 * j) * 128 + c];
          acc4[j] += w.x * xv.x + w.y * xv.y + w.z * xv.z + w.w * xv.w;
        }
      }
#pragma unroll
      for (int j = 0; j < 4; ++j)
        hc[(pg + 4 * j) * 68 + o] = fmaxf(acc4[j], 0.f);
    }
    __syncthreads();
    for (int i = tid; i < 128 * 64; i += 256) {
      int r = i >> 6, c = i & 63;
      wb[r * 68 + c] = ldany(aw2, (size_t)r * AAD + ac * 64 + c, faw2);
    }
    __syncthreads();
    for (int a = 0; a < 64; a += 4) {
      float4 w = *(const float4*)&wb[d * 68 + a];
#pragma unroll
      for (int j = 0; j < 8; ++j) {
        const float4 hv = *(const float4*)&hc[(kg + 2 * j) * 68 + a];
        accs[j] += w.x * hv.x + w.y * hv.y + w.z * hv.z + w.w * hv.w;
      }
    }
  }
  __syncthreads();
#pragma unroll
  for (int j = 0; j < 8; ++j) sld[d * 17 + kg + 2 * j] = accs[j];
  __syncthreads();
  if (tid < 128) {
    float m = __uint_as_float(0xff800000u);
#pragma unroll
    for (int k2 = 0; k2 < 16; ++k2) m = fmaxf(m, sld[tid * 17 + k2]);
    float e[16];
    float sum = 0.f;
#pragma unroll
    for (int k2 = 0; k2 < 16; ++k2) { e[k2] = expf(sld[tid * 17 + k2] - m); sum += e[k2]; }
    float inv = 1.f / (1.f + sum);
    float a = 0.f, vv = vfe[tid];
#pragma unroll
    for (int k2 = 0; k2 < 16; ++k2)
      a += (e[k2] * inv) * (vv + b2f(embs[k2 * 128 + tid]));
    aggT[(size_t)p * 128 + tid] = __float2bfloat16(a);
  }
}

// ---------- token-major bf16 (P,128) -> (B,128,N) output (dtype per flag) ----------
__global__ __launch_bounds__(256) void out_kern(const bf16* __restrict__ yT,
                                                void* __restrict__ outp,
                                                const int* __restrict__ flags, int ofIdx) {
  __shared__ float tile[64][65];
  const int f32 = flags[ofIdx];
  int b = blockIdx.z, n0 = blockIdx.x * 64, c0 = blockIdx.y * 64;
  int tx = threadIdx.x & 63, ty = threadIdx.x >> 6;
  for (int r = ty; r < 64; r += 4)
    tile[r][tx] = b2f(yT[(size_t)(b * NN + n0 + r) * 128 + c0 + tx]);
  __syncthreads();
  for (int r = ty; r < 64; r += 4) {
    size_t oi = (size_t)(b * CCH + c0 + r) * NN + n0 + tx;
    float v = tile[tx][r];
    if (f32) ((float*)outp)[oi] = v;
    else ((bf16*)outp)[oi] = __float2bfloat16(v);
  }
}

extern "C" void kernel_launch(void* const* d_in, const int* in_sizes, int n_in,
                              void* d_out, int out_size, void* d_ws, size_t ws_size,
                              hipStream_t stream) {
  const void* mv_w1 = d_in[4];  const void* mv_b1 = d_in[5];
  const void* mv_w2 = d_in[6];  const void* mv_b2 = d_in[7];
  const void* mv_ws = d_in[8];  const void* mv_bs = d_in[9];
  const void* wk    = d_in[10]; const void* bk    = d_in[11];
  const void* wq    = d_in[12]; const void* bq    = d_in[13];
  const void* wv    = d_in[14]; const void* bv    = d_in[15];
  const void* xyz_w1= d_in[16]; const void* xyz_b1= d_in[17];
  const void* xyz_w2= d_in[18]; const void* xyz_b2= d_in[19];
  const void* pos_w1= d_in[20]; const void* pos_b1= d_in[21];
  const void* pos_w2= d_in[22]; const void* pos_b2= d_in[23];
  const void* xat_w1= d_in[24]; const void* xat_b1= d_in[25];
  const void* xat_w2= d_in[26]; const void* xat_b2= d_in[27];
  const void* at_w1 = d_in[28]; const void* at_b1 = d_in[29];
  const void* at_w2 = d_in[30]; const void* at_b2 = d_in[31];
  const void* wkq   = d_in[32]; const void* bkq   = d_in[33];
  const void* wend  = d_in[34]; const void* bend  = d_in[35];

  // workspace layout (~16.8 MB): flags | bf16 features | fp32 coords | idx
  int* flags = (int*)d_ws;
  bf16* catT = (bf16*)((float*)d_ws + 64);        // P x 256
  bf16* v0   = catT + (size_t)PP * 256;           // identity, lives to end
  bf16* kT   = v0 + (size_t)PP * 128;             // lives to attn2
  bf16* qT   = kT + (size_t)PP * 128;             // lives to attn2
  bf16* sE   = qT + (size_t)PP * 128;             // vT, then value2
  bf16* sF   = sE + (size_t)PP * 128;             // tmp, agg1, agg2
  bf16* sG   = sF + (size_t)PP * 128;             // shortb, val1, yT
  float* xyzT = (float*)(sG + (size_t)PP * 128);  // P x 4
  float* posT = xyzT + (size_t)PP * 4;
  int* idxb = (int*)(posT + (size_t)PP * 4);      // P x 16 (idx1 then idx2)

  PtrArr pa;
  for (int i = 0; i < 36; ++i) { pa.p[i] = d_in[i]; pa.n[i] = in_sizes[i]; }
  sniff_kern<<<dim3(36), 256, 0, stream>>>(pa, flags);

  dim3 trg(32, 2, 4);
  tr_in_kern<<<trg, 256, 0, stream>>>(d_in[2], flags, 2, catT, 128, 256, 0);     // key
  tr_in_kern<<<trg, 256, 0, stream>>>(d_in[3], flags, 3, catT, 128, 256, 128);   // query
  tr_coords_kern<<<dim3(128), 256, 0, stream>>>(d_in[0], flags, 0, xyzT, 3);
  tr_coords_kern<<<dim3(128), 256, 0, stream>>>(d_in[1], flags, 1, posT, 2);

  dim3 lg(PP / 16, 2);
  // MLP_Res frontend
  linear_kern<<<lg, 256, 0, stream>>>(catT, 256, 256, 8, mv_w1, mv_b1, flags, 4, 5, nullptr, sF, 128, 1);
  linear_kern<<<lg, 256, 0, stream>>>(catT, 256, 256, 8, mv_ws, mv_bs, flags, 8, 9, nullptr, sG, 128, 0);
  linear_kern<<<lg, 256, 0, stream>>>(sF,   128, 128, 7, mv_w2, mv_b2, flags, 6, 7, sG,      v0, 128, 0);
  // k, q, v
  linear_kern<<<lg, 256, 0, stream>>>(catT,       256, 128, 7, wk, bk, flags, 10, 11, nullptr, kT, 128, 0);
  linear_kern<<<lg, 256, 0, stream>>>(catT + 128, 256, 128, 7, wq, bq, flags, 12, 13, nullptr, qT, 128, 0);
  linear_kern<<<lg, 256, 0, stream>>>(v0,         128, 128, 7, wv, bv, flags, 14, 15, nullptr, sE, 128, 0);
  // block 1 (xyz space): center=k, gathered=q, vfeat=v
  knn_kern<<<dim3(PP), 256, 0, stream>>>(xyzT, idxb);
  attn_kern<<<dim3(PP), 256, 0, stream>>>(kT, qT, xyzT, sE, idxb, 3,
                                          xyz_w1, xyz_b1, xyz_w2, xyz_b2,
                                          xat_w1, xat_b1, xat_w2, xat_b2,
                                          flags, 16, 24, sF);                    // agg1
  linear_kern<<<lg, 256, 0, stream>>>(sF, 128, 128, 7, wkq, bkq, flags, 32, 33, v0, sG, 128, 0);      // val1
  linear_kern<<<lg, 256, 0, stream>>>(sG, 128, 128, 7, wv,  bv,  flags, 14, 15, nullptr, sE, 128, 0); // value2
  // block 2 (pos space): center=q, gathered=k, vfeat=value2
  knn_kern<<<dim3(PP), 256, 0, stream>>>(posT, idxb);
  attn_kern<<<dim3(PP), 256, 0, stream>>>(qT, kT, posT, sE, idxb, 2,
                                          pos_w1, pos_b1, pos_w2, pos_b2,
                                          at_w1, at_b1, at_w2, at_b2,
                                          flags, 20, 28, sF);                    // agg2
  linear_kern<<<lg, 256, 0, stream>>>(sF, 128, 128, 7, wend, bend, flags, 34, 35, v0, sG, 128, 0);    // yT
  out_kern<<<trg, 256, 0, stream>>>(sG, d_out, flags, 2);
}

// Round 3
// 939.694 us; speedup vs baseline: 4.7036x; 4.7036x over previous
//
#include <hip/hip_runtime.h>
#include <hip/hip_bf16.h>

typedef __hip_bfloat16 bf16;

#define BB 4
#define NN 2048
#define CCH 128
#define DDM 128
#define KNB 16
#define HHD 64
#define AAD 512
#define PP (BB*NN)

typedef __attribute__((ext_vector_type(8))) short short8;
typedef __attribute__((ext_vector_type(16))) float f32x16;

__device__ __forceinline__ float b2f(bf16 x) { return __bfloat162float(x); }
__device__ __forceinline__ bf16 f2b(float x) { return __float2bfloat16(x); }

__device__ __forceinline__ float ldany(const void* p, size_t i, int f32) {
  return f32 ? ((const float*)p)[i] : __bfloat162float(((const bf16*)p)[i]);
}

__device__ __forceinline__ long pack4(float a, float b, float c, float d) {
  union { bf16 h[4]; long l; } u;
  u.h[0] = f2b(a); u.h[1] = f2b(b); u.h[2] = f2b(c); u.h[3] = f2b(d);
  return u.l;
}
__device__ __forceinline__ void unpack4(long l, float* o) {
  union { bf16 h[4]; long l; } u; u.l = l;
  o[0] = b2f(u.h[0]); o[1] = b2f(u.h[1]); o[2] = b2f(u.h[2]); o[3] = b2f(u.h[3]);
}

__device__ __forceinline__ short8 ldfrag(const bf16* base, int row, int stride, int k0, int hl) {
  const bf16* p = base + (size_t)row * stride + k0 + (hl << 3);
  union { short8 v; long l[2]; } u;
  u.l[0] = *(const long*)p;
  u.l[1] = *(const long*)(p + 4);
  return u.v;
}

__device__ __forceinline__ f32x16 MFMA(short8 a, short8 b, f32x16 c) {
  return __builtin_amdgcn_mfma_f32_32x32x16_bf16(a, b, c, 0, 0, 0);
}

__device__ __forceinline__ void gload16(const bf16* g, bf16* l) {
  __builtin_amdgcn_global_load_lds((const __attribute__((address_space(1))) void*)g,
                                   (__attribute__((address_space(3))) void*)l, 16, 0, 0);
}

struct PtrArr { const void* p[36]; int n[36]; };

// ---------- dtype sniffer ----------
__global__ __launch_bounds__(256) void sniff_kern(PtrArr pa, int* __restrict__ flags) {
  int t = blockIdx.x;
  const bf16* x = (const bf16*)pa.p[t];
  int n = pa.n[t]; if (n > 4096) n = 4096;
  __shared__ int cnt;
  if (threadIdx.x == 0) cnt = 0;
  __syncthreads();
  int c = 0;
  for (int i = threadIdx.x; i < n; i += 256) {
    float v = fabsf(__bfloat162float(x[i]));
    if (v == 0.f || (v >= 1e-6f && v <= 1024.f)) c++;
  }
  atomicAdd(&cnt, c);
  __syncthreads();
  if (threadIdx.x == 0) flags[t] = (cnt >= (n * 7) / 8) ? 0 : 1;
}

// ---------- transpose (B,C,N) raw -> token-major (P, ldd) bf16 ----------
__global__ __launch_bounds__(256) void tr_in_kern(const void* __restrict__ src,
                                                  const int* __restrict__ flags, int fIdx,
                                                  bf16* __restrict__ dst,
                                                  int C, int ldd, int coff) {
  __shared__ float tile[64][65];
  const int f32 = flags[fIdx];
  int b = blockIdx.z, n0 = blockIdx.x * 64, c0 = blockIdx.y * 64;
  int tx = threadIdx.x & 63, ty = threadIdx.x >> 6;
  for (int r = ty; r < 64; r += 4)
    tile[r][tx] = ldany(src, (size_t)(b * C + c0 + r) * NN + n0 + tx, f32);
  __syncthreads();
  for (int r = ty; r < 64; r += 4)
    dst[(size_t)(b * NN + n0 + r) * ldd + coff + c0 + tx] = __float2bfloat16(tile[tx][r]);
}

// ---------- coords (B,dd,N) raw -> (P,4) fp32 ----------
__global__ __launch_bounds__(256) void tr_coords_kern(const void* __restrict__ src,
                                                      const int* __restrict__ flags, int fIdx,
                                                      float* __restrict__ dst, int dd) {
  const int f32 = flags[fIdx];
  int i = blockIdx.x * 256 + threadIdx.x;
  if (i >= PP * 4) return;
  int p = i >> 2, j = i & 3;
  int b = p >> 11, n = p & (NN - 1);
  dst[i] = (j < dd) ? ldany(src, (size_t)(b * dd + j) * NN + n, f32) : 0.f;
}

// ---------- token-major linear ----------
__global__ __launch_bounds__(256) void linear_kern(
    const bf16* __restrict__ X, int ldx, int Cin, int cinLog,
    const void* __restrict__ W, const void* __restrict__ bias,
    const int* __restrict__ flags, int wIdx, int bIdx,
    const bf16* __restrict__ add, bf16* __restrict__ out, int ldout, int relu) {
  __shared__ __attribute__((aligned(16))) float xt[16 * 256];
  __shared__ __attribute__((aligned(16))) float wbuf[64 * 132];
  const int wf = flags[wIdx], bfl = flags[bIdx];
  int tid = threadIdx.x;
  int p0 = blockIdx.x * 16, o0 = blockIdx.y * 64;
  for (int i = tid; i < 16 * Cin; i += 256) {
    int pl = i >> cinLog, c = i & (Cin - 1);
    xt[i] = b2f(X[(size_t)(p0 + pl) * ldx + c]);
  }
  int o = tid & 63, pg = tid >> 6;
  float bv = ldany(bias, o0 + o, bfl);
  float acc[4] = {bv, bv, bv, bv};
  for (int ch = 0; ch < Cin; ch += 128) {
    __syncthreads();
    for (int i = tid; i < 64 * 128; i += 256) {
      int r = i >> 7, c = i & 127;
      wbuf[r * 132 + c] = ldany(W, (size_t)(o0 + r) * Cin + ch + c, wf);
    }
    __syncthreads();
    for (int c = 0; c < 128; c += 4) {
      float4 w = *(const float4*)&wbuf[o * 132 + c];
#pragma unroll
      for (int j = 0; j < 4; ++j) {
        const float4 xv = *(const float4*)&xt[((pg + 4 * j) << cinLog) + ch + c];
        acc[j] += w.x * xv.x + w.y * xv.y + w.z * xv.z + w.w * xv.w;
      }
    }
  }
#pragma unroll
  for (int j = 0; j < 4; ++j) {
    int p = p0 + pg + 4 * j;
    float v = acc[j];
    if (add) v += b2f(add[(size_t)p * 128 + o0 + o]);
    if (relu) v = fmaxf(v, 0.f);
    out[(size_t)p * ldout + o0 + o] = __float2bfloat16(v);
  }
}

// ---------- kNN (stable argsort semantics) ----------
__global__ __launch_bounds__(256) void knn_kern(const float* __restrict__ coordsT,
                                                int* __restrict__ idxout) {
  __shared__ __attribute__((aligned(16))) float4 cds[NN];
  __shared__ float d2s[NN];
  __shared__ unsigned long long red[4];
  int p = blockIdx.x, b = p >> 11, n = p & (NN - 1);
  int tid = threadIdx.x;
  for (int j = tid; j < NN; j += 256)
    cds[j] = *(const float4*)&coordsT[((size_t)(b << 11) + j) * 4];
  __syncthreads();
  float4 cc = cds[n];
  float sqi = __fadd_rn(__fadd_rn(__fmul_rn(cc.x, cc.x), __fmul_rn(cc.y, cc.y)),
                        __fmul_rn(cc.z, cc.z));
  for (int j = tid; j < NN; j += 256) {
    float4 q = cds[j];
    float sqj = __fadd_rn(__fadd_rn(__fmul_rn(q.x, q.x), __fmul_rn(q.y, q.y)),
                          __fmul_rn(q.z, q.z));
    float dt  = __fadd_rn(__fadd_rn(__fmul_rn(cc.x, q.x), __fmul_rn(cc.y, q.y)),
                          __fmul_rn(cc.z, q.z));
    d2s[j] = __fsub_rn(__fadd_rn(sqi, sqj), __fmul_rn(2.f, dt));
  }
  __syncthreads();
  for (int t = 0; t < KNB; ++t) {
    unsigned long long best = ~0ull;
    for (int j = tid; j < NN; j += 256) {
      unsigned u = __float_as_uint(d2s[j]);
      u = (u & 0x80000000u) ? ~u : (u | 0x80000000u);
      unsigned long long key = ((unsigned long long)u << 32) | (unsigned)j;
      best = best < key ? best : key;
    }
#pragma unroll
    for (int off = 32; off > 0; off >>= 1) {
      unsigned long long o2 = __shfl_down(best, off);
      best = best < o2 ? best : o2;
    }
    if ((tid & 63) == 0) red[tid >> 6] = best;
    __syncthreads();
    if (tid == 0) {
      unsigned long long m = red[0];
      for (int w = 1; w < 4; ++w) m = m < red[w] ? m : red[w];
      int j = (int)(m & 0xffffffffu);
      idxout[(size_t)p * KNB + t] = j;
      d2s[j] = __uint_as_float(0x7f800000u);
    }
    __syncthreads();
  }
}

// ---------- weight-image prep: pad weights into LDS-blob layout + fp32 biases ----------
__global__ __launch_bounds__(256) void prep_kern(
    const void* cw1, const void* cb1, const void* cw2, const void* cb2,
    const void* aw1, const void* ab1, const void* aw2, const void* ab2,
    const int* __restrict__ flags, int cIdx, int aIdx, int dd,
    bf16* __restrict__ w1img, bf16* __restrict__ w2img, bf16* __restrict__ cw2img,
    float* __restrict__ fb) {
  int i = blockIdx.x * 256 + threadIdx.x;
  const int fcw1 = flags[cIdx], fcb1 = flags[cIdx + 1];
  const int fcw2 = flags[cIdx + 2], fcb2 = flags[cIdx + 3];
  const int faw1 = flags[aIdx], fab1 = flags[aIdx + 1];
  const int faw2 = flags[aIdx + 2], fab2 = flags[aIdx + 3];
  float* ab1f = fb;          // 512
  float* ab2f = fb + 512;    // 128
  float* cb1f = fb + 640;    // 64
  float* cb2f = fb + 704;    // 128
  float* cw1f = fb + 832;    // 192
  if (i < 65536) {                       // w1img: [h_glob 512][132]
    int hg = i >> 7, c = i & 127;
    w1img[(size_t)hg * 132 + c] = f2b(ldany(aw1, i, faw1));
  } else if (i < 131072) {               // w2img: [ac*128+o][132] col=h_local
    int j = i - 65536;
    int o = j >> 9, hh = j & 511;
    int ac = hh >> 7, hloc = hh & 127;
    w2img[(size_t)(ac * 128 + o) * 132 + hloc] = f2b(ldany(aw2, j, faw2));
  } else if (i < 139264) {               // cw2img: [o 128][68]
    int j = i - 131072;
    int o = j >> 6, h = j & 63;
    cw2img[o * 68 + h] = f2b(ldany(cw2, j, fcw2));
  } else if (i < 139776) {
    int j = i - 139264; ab1f[j] = ldany(ab1, j, fab1);
  } else if (i < 139904) {
    int j = i - 139776; ab2f[j] = ldany(ab2, j, fab2);
  } else if (i < 139968) {
    int j = i - 139904; cb1f[j] = ldany(cb1, j, fcb1);
  } else if (i < 140096) {
    int j = i - 139968; cb2f[j] = ldany(cb2, j, fcb2);
  } else if (i < 140288) {
    int j = i - 140096;
    int h = j / 3, c = j % 3;
    cw1f[j] = (c < dd) ? ldany(cw1, h * dd + c, fcw1) : 0.f;
  }
}

// ---------- MFMA fused kNN attention: 8 points / 128 tokens per workgroup ----------
#define SMEM_BYTES 157696
__global__ __launch_bounds__(512, 2) void attn_mfma(
    const bf16* __restrict__ centerT, const bf16* __restrict__ gatherT,
    const float* __restrict__ coordsT, const bf16* __restrict__ vfeatT,
    const int* __restrict__ idx,
    const bf16* __restrict__ w1img, const bf16* __restrict__ w2img,
    const bf16* __restrict__ cw2img, const float* __restrict__ fb,
    bf16* __restrict__ aggT) {
  extern __shared__ char smem[];
  bf16* XS  = (bf16*)(smem);            // [128][132]  x = kq_rel + emb
  bf16* HT  = (bf16*)(smem + 33792);    // [128][132]  hidden chunk [m][h]
  bf16* W1C = (bf16*)(smem + 67584);    // [128][132]  (pre-loop: cw2 image [128][68])
  bf16* W2C = (bf16*)(smem + 101376);   // [128][132]
  bf16* HC  = (bf16*)(smem + 135168);   // [128][68]   coord hidden
  bf16* CFE = (bf16*)(smem + 152576);   // [8][128]
  bf16* VF  = (bf16*)(smem + 154624);   // [8][128]
  int*  NID = (int*)(smem + 156672);    // [128]
  const float* ab1f = fb;
  const float* ab2f = fb + 512;
  const float* cb1f = fb + 640;
  const float* cb2f = fb + 704;
  const float* cw1f = fb + 832;

  int tid = threadIdx.x, lane = tid & 63, wv = tid >> 6;
  int hl = lane >> 5, cA = lane & 31;
  int P0 = blockIdx.x * 8, b = P0 >> 11;

  // phase 0: issue cw2 image load; stage NID/CFE/VF
  for (int i = tid; i < 1088; i += 512) gload16(cw2img + i * 8, W1C + i * 8);
  if (tid < 128) NID[tid] = (b << 11) + idx[(size_t)(P0 + (tid >> 4)) * KNB + (tid & 15)];
  for (int i = tid; i < 1024; i += 512) {
    int g = i >> 7, d = i & 127;
    CFE[i] = centerT[(size_t)(P0 + g) * 128 + d];
    VF[i]  = vfeatT[(size_t)(P0 + g) * 128 + d];
  }
  __syncthreads();

  // phase 1: coord hidden HC + XS base (= cfe - gathered)
  {
    int m = tid >> 2, sub = tid & 3;
    float4 ccd = *(const float4*)&coordsT[(size_t)(P0 + (m >> 4)) * 4];
    float4 nbd = *(const float4*)&coordsT[(size_t)NID[m] * 4];
    float r0 = ccd.x - nbd.x, r1 = ccd.y - nbd.y, r2 = ccd.z - nbd.z;
    int h0 = sub * 16;
    for (int hh = h0; hh < h0 + 16; hh += 4) {
      float a0 = fmaxf(cb1f[hh+0] + cw1f[(hh+0)*3]*r0 + cw1f[(hh+0)*3+1]*r1 + cw1f[(hh+0)*3+2]*r2, 0.f);
      float a1 = fmaxf(cb1f[hh+1] + cw1f[(hh+1)*3]*r0 + cw1f[(hh+1)*3+1]*r1 + cw1f[(hh+1)*3+2]*r2, 0.f);
      float a2 = fmaxf(cb1f[hh+2] + cw1f[(hh+2)*3]*r0 + cw1f[(hh+2)*3+1]*r1 + cw1f[(hh+2)*3+2]*r2, 0.f);
      float a3 = fmaxf(cb1f[hh+3] + cw1f[(hh+3)*3]*r0 + cw1f[(hh+3)*3+1]*r1 + cw1f[(hh+3)*3+2]*r2, 0.f);
      *(long*)&HC[m * 68 + hh] = pack4(a0, a1, a2, a3);
    }
    const bf16* grow = gatherT + (size_t)NID[m] * 128 + sub * 32;
    const bf16* crow = CFE + ((m >> 4) << 7) + sub * 32;
    for (int j = 0; j < 32; j += 4) {
      float gv[4], cv[4];
      unpack4(*(const long*)(grow + j), gv);
      unpack4(*(const long*)(crow + j), cv);
      *(long*)&XS[m * 132 + sub * 32 + j] =
          pack4(cv[0] - gv[0], cv[1] - gv[1], cv[2] - gv[2], cv[3] - gv[3]);
    }
  }
  __syncthreads();

  int r0s = (wv & 3) * 32;     // output-row strip (o / h)
  int mt0 = (wv >> 2) * 64;    // token strip (2 tiles of 32)

  // phase 2: emb GEMM (C_e[o][m] = cw2 @ HC + cb2), RMW into XS
  {
    f32x16 eacc[2];
#pragma unroll
    for (int r = 0; r < 16; ++r) {
      int o = r0s + (r & 3) + 8 * (r >> 2) + 4 * hl;
      float bv = cb2f[o];
      eacc[0][r] = bv; eacc[1][r] = bv;
    }
    for (int k0 = 0; k0 < 64; k0 += 16) {
      short8 af = ldfrag(W1C, r0s + cA, 68, k0, hl);
      short8 b0 = ldfrag(HC, mt0 + cA, 68, k0, hl);
      short8 b1 = ldfrag(HC, mt0 + 32 + cA, 68, k0, hl);
      eacc[0] = MFMA(af, b0, eacc[0]);
      eacc[1] = MFMA(af, b1, eacc[1]);
    }
#pragma unroll
    for (int t = 0; t < 2; ++t) {
      int m = mt0 + t * 32 + cA;
#pragma unroll
      for (int q = 0; q < 4; ++q) {
        int ob = r0s + 8 * q + 4 * hl;
        bf16* px = &XS[m * 132 + ob];
        float xv[4];
        unpack4(*(long*)px, xv);
        *(long*)px = pack4(xv[0] + eacc[t][4*q+0], xv[1] + eacc[t][4*q+1],
                           xv[2] + eacc[t][4*q+2], xv[3] + eacc[t][4*q+3]);
      }
    }
  }
  __syncthreads();

  // preload XS B-fragments into registers (reused by all 4 chunks)
  short8 xsf[2][8];
#pragma unroll
  for (int ks = 0; ks < 8; ++ks) {
    xsf[0][ks] = ldfrag(XS, mt0 + cA, 132, ks * 16, hl);
    xsf[1][ks] = ldfrag(XS, mt0 + 32 + cA, 132, ks * 16, hl);
  }
  // logits accumulator (bias-init)
  f32x16 acc2[2];
#pragma unroll
  for (int r = 0; r < 16; ++r) {
    int o = r0s + (r & 3) + 8 * (r >> 2) + 4 * hl;
    float bv = ab2f[o];
    acc2[0][r] = bv; acc2[1][r] = bv;
  }

  // chunk loop: 4 x 128 hidden
  for (int ac = 0; ac < 4; ++ac) {
    __syncthreads();  // prior chunk done with W1C/W2C/HT; XS preload done
    for (int i = tid; i < 2112; i += 512) gload16(w1img + (size_t)ac * 16896 + i * 8, W1C + i * 8);
    for (int i = tid; i < 2112; i += 512) gload16(w2img + (size_t)ac * 16896 + i * 8, W2C + i * 8);
    __syncthreads();  // drains vmcnt: images resident
    // GEMM1: H[h][m] = relu(W1 @ X + ab1)
    f32x16 acc1[2];
#pragma unroll
    for (int r = 0; r < 16; ++r) {
      int h = r0s + (r & 3) + 8 * (r >> 2) + 4 * hl;
      float bv = ab1f[ac * 128 + h];
      acc1[0][r] = bv; acc1[1][r] = bv;
    }
#pragma unroll
    for (int ks = 0; ks < 8; ++ks) {
      short8 af = ldfrag(W1C, r0s + cA, 132, ks * 16, hl);
      acc1[0] = MFMA(af, xsf[0][ks], acc1[0]);
      acc1[1] = MFMA(af, xsf[1][ks], acc1[1]);
    }
#pragma unroll
    for (int t = 0; t < 2; ++t) {
      int m = mt0 + t * 32 + cA;
#pragma unroll
      for (int q = 0; q < 4; ++q) {
        int hb = r0s + 8 * q + 4 * hl;
        *(long*)&HT[m * 132 + hb] =
            pack4(fmaxf(acc1[t][4*q+0], 0.f), fmaxf(acc1[t][4*q+1], 0.f),
                  fmaxf(acc1[t][4*q+2], 0.f), fmaxf(acc1[t][4*q+3], 0.f));
      }
    }
    __syncthreads();  // HT complete
    // GEMM2: logits[o][m] += W2 @ H
#pragma unroll
    for (int ks = 0; ks < 8; ++ks) {
      short8 af = ldfrag(W2C, r0s + cA, 132, ks * 16, hl);
      short8 b0 = ldfrag(HT, mt0 + cA, 132, ks * 16, hl);
      short8 b1 = ldfrag(HT, mt0 + 32 + cA, 132, ks * 16, hl);
      acc2[0] = MFMA(af, b0, acc2[0]);
      acc2[1] = MFMA(af, b1, acc2[1]);
    }
  }

  // softmax-one over kk (16-lane groups) + aggregation
#pragma unroll
  for (int t = 0; t < 2; ++t) {
    int m = mt0 + t * 32 + cA;
    int g = m >> 4;
    float a[16];
#pragma unroll
    for (int r = 0; r < 16; ++r) {
      float x = acc2[t][r];
      float mx = x;
      mx = fmaxf(mx, __shfl_xor(mx, 1, 16));
      mx = fmaxf(mx, __shfl_xor(mx, 2, 16));
      mx = fmaxf(mx, __shfl_xor(mx, 4, 16));
      mx = fmaxf(mx, __shfl_xor(mx, 8, 16));
      float e = __expf(x - mx);
      float s = e;
      s += __shfl_xor(s, 1, 16);
      s += __shfl_xor(s, 2, 16);
      s += __shfl_xor(s, 4, 16);
      s += __shfl_xor(s, 8, 16);
      a[r] = e / (1.f + s);
    }
#pragma unroll
    for (int q = 0; q < 4; ++q) {
      int ob = r0s + 8 * q + 4 * hl;
      float xv[4], gv[4], vv[4], cv[4];
      unpack4(*(long*)&XS[m * 132 + ob], xv);
      unpack4(*(const long*)(gatherT + (size_t)NID[m] * 128 + ob), gv);
      unpack4(*(long*)&VF[(g << 7) + ob], vv);
      unpack4(*(long*)&CFE[(g << 7) + ob], cv);
      float p0 = a[4*q+0] * (vv[0] - cv[0] + xv[0] + gv[0]);
      float p1 = a[4*q+1] * (vv[1] - cv[1] + xv[1] + gv[1]);
      float p2 = a[4*q+2] * (vv[2] - cv[2] + xv[2] + gv[2]);
      float p3 = a[4*q+3] * (vv[3] - cv[3] + xv[3] + gv[3]);
#pragma unroll
      for (int s = 1; s < 16; s <<= 1) {
        p0 += __shfl_xor(p0, s, 16);
        p1 += __shfl_xor(p1, s, 16);
        p2 += __shfl_xor(p2, s, 16);
        p3 += __shfl_xor(p3, s, 16);
      }
      if ((lane & 15) == 0)
        *(long*)(aggT + (size_t)(P0 + g) * 128 + ob) = pack4(p0, p1, p2, p3);
    }
  }
}

// ---------- token-major bf16 (P,128) -> (B,128,N) output ----------
__global__ __launch_bounds__(256) void out_kern(const bf16* __restrict__ yT,
                                                void* __restrict__ outp,
                                                const int* __restrict__ flags, int ofIdx) {
  __shared__ float tile[64][65];
  const int f32 = flags[ofIdx];
  int b = blockIdx.z, n0 = blockIdx.x * 64, c0 = blockIdx.y * 64;
  int tx = threadIdx.x & 63, ty = threadIdx.x >> 6;
  for (int r = ty; r < 64; r += 4)
    tile[r][tx] = b2f(yT[(size_t)(b * NN + n0 + r) * 128 + c0 + tx]);
  __syncthreads();
  for (int r = ty; r < 64; r += 4) {
    size_t oi = (size_t)(b * CCH + c0 + r) * NN + n0 + tx;
    float v = tile[tx][r];
    if (f32) ((float*)outp)[oi] = v;
    else ((bf16*)outp)[oi] = __float2bfloat16(v);
  }
}

extern "C" void kernel_launch(void* const* d_in, const int* in_sizes, int n_in,
                              void* d_out, int out_size, void* d_ws, size_t ws_size,
                              hipStream_t stream) {
  const void* mv_w1 = d_in[4];  const void* mv_b1 = d_in[5];
  const void* mv_w2 = d_in[6];  const void* mv_b2 = d_in[7];
  const void* mv_ws = d_in[8];  const void* mv_bs = d_in[9];
  const void* wk    = d_in[10]; const void* bk    = d_in[11];
  const void* wq    = d_in[12]; const void* bq    = d_in[13];
  const void* wv    = d_in[14]; const void* bv    = d_in[15];
  const void* wkq   = d_in[32]; const void* bkq   = d_in[33];
  const void* wend  = d_in[34]; const void* bend  = d_in[35];

  // workspace layout
  int* flags = (int*)d_ws;
  bf16* catT = (bf16*)((float*)d_ws + 64);        // P x 256
  bf16* v0   = catT + (size_t)PP * 256;
  bf16* kT   = v0 + (size_t)PP * 128;
  bf16* qT   = kT + (size_t)PP * 128;
  bf16* sE   = qT + (size_t)PP * 128;             // vT, then value2
  bf16* sF   = sE + (size_t)PP * 128;             // tmp, agg1, agg2
  bf16* sG   = sF + (size_t)PP * 128;             // shortb, val1, yT
  float* xyzT = (float*)(sG + (size_t)PP * 128);  // P x 4
  float* posT = xyzT + (size_t)PP * 4;
  int* idxb = (int*)(posT + (size_t)PP * 4);      // P x 16
  bf16* w1i1 = (bf16*)(idxb + (size_t)PP * KNB);  // 4*128*132
  bf16* w2i1 = w1i1 + 67584;
  bf16* cw2i1 = w2i1 + 67584;                     // 128*68
  bf16* w1i2 = cw2i1 + 8704;
  bf16* w2i2 = w1i2 + 67584;
  bf16* cw2i2 = w2i2 + 67584;
  float* fb1 = (float*)(cw2i2 + 8704);            // 1024 floats
  float* fb2 = fb1 + 1024;

  PtrArr pa;
  for (int i = 0; i < 36; ++i) { pa.p[i] = d_in[i]; pa.n[i] = in_sizes[i]; }
  sniff_kern<<<dim3(36), 256, 0, stream>>>(pa, flags);

  prep_kern<<<dim3(548), 256, 0, stream>>>(d_in[16], d_in[17], d_in[18], d_in[19],
                                           d_in[24], d_in[25], d_in[26], d_in[27],
                                           flags, 16, 24, 3, w1i1, w2i1, cw2i1, fb1);
  prep_kern<<<dim3(548), 256, 0, stream>>>(d_in[20], d_in[21], d_in[22], d_in[23],
                                           d_in[28], d_in[29], d_in[30], d_in[31],
                                           flags, 20, 28, 2, w1i2, w2i2, cw2i2, fb2);

  dim3 trg(32, 2, 4);
  tr_in_kern<<<trg, 256, 0, stream>>>(d_in[2], flags, 2, catT, 128, 256, 0);
  tr_in_kern<<<trg, 256, 0, stream>>>(d_in[3], flags, 3, catT, 128, 256, 128);
  tr_coords_kern<<<dim3(128), 256, 0, stream>>>(d_in[0], flags, 0, xyzT, 3);
  tr_coords_kern<<<dim3(128), 256, 0, stream>>>(d_in[1], flags, 1, posT, 2);

  dim3 lg(PP / 16, 2);
  linear_kern<<<lg, 256, 0, stream>>>(catT, 256, 256, 8, mv_w1, mv_b1, flags, 4, 5, nullptr, sF, 128, 1);
  linear_kern<<<lg, 256, 0, stream>>>(catT, 256, 256, 8, mv_ws, mv_bs, flags, 8, 9, nullptr, sG, 128, 0);
  linear_kern<<<lg, 256, 0, stream>>>(sF,   128, 128, 7, mv_w2, mv_b2, flags, 6, 7, sG,      v0, 128, 0);
  linear_kern<<<lg, 256, 0, stream>>>(catT,       256, 128, 7, wk, bk, flags, 10, 11, nullptr, kT, 128, 0);
  linear_kern<<<lg, 256, 0, stream>>>(catT + 128, 256, 128, 7, wq, bq, flags, 12, 13, nullptr, qT, 128, 0);
  linear_kern<<<lg, 256, 0, stream>>>(v0,         128, 128, 7, wv, bv, flags, 14, 15, nullptr, sE, 128, 0);

  hipFuncSetAttribute((const void*)attn_mfma, hipFuncAttributeMaxDynamicSharedMemorySize, SMEM_BYTES);

  // block 1 (xyz): center=k, gathered=q, vfeat=v
  knn_kern<<<dim3(PP), 256, 0, stream>>>(xyzT, idxb);
  attn_mfma<<<dim3(PP / 8), 512, SMEM_BYTES, stream>>>(kT, qT, xyzT, sE, idxb,
                                                       w1i1, w2i1, cw2i1, fb1, sF);
  linear_kern<<<lg, 256, 0, stream>>>(sF, 128, 128, 7, wkq, bkq, flags, 32, 33, v0, sG, 128, 0);
  linear_kern<<<lg, 256, 0, stream>>>(sG, 128, 128, 7, wv,  bv,  flags, 14, 15, nullptr, sE, 128, 0);
  // block 2 (pos): center=q, gathered=k, vfeat=value2
  knn_kern<<<dim3(PP), 256, 0, stream>>>(posT, idxb);
  attn_mfma<<<dim3(PP / 8), 512, SMEM_BYTES, stream>>>(qT, kT, posT, sE, idxb,
                                                       w1i2, w2i2, cw2i2, fb2, sF);
  linear_kern<<<lg, 256, 0, stream>>>(sF, 128, 128, 7, wend, bend, flags, 34, 35, v0, sG, 128, 0);
  out_kern<<<trg, 256, 0, stream>>>(sG, d_out, flags, 2);
}

// Round 4
// 774.718 us; speedup vs baseline: 5.7052x; 1.2129x over previous
//
#include <hip/hip_runtime.h>
#include <hip/hip_bf16.h>

typedef __hip_bfloat16 bf16;
typedef unsigned long long ull;

#define BB 4
#define NN 2048
#define CCH 128
#define DDM 128
#define KNB 16
#define HHD 64
#define AAD 512
#define PP (BB*NN)

typedef __attribute__((ext_vector_type(8))) short short8;
typedef __attribute__((ext_vector_type(16))) float f32x16;

__device__ __forceinline__ float b2f(bf16 x) { return __bfloat162float(x); }
__device__ __forceinline__ bf16 f2b(float x) { return __float2bfloat16(x); }

__device__ __forceinline__ float ldany(const void* p, size_t i, int f32) {
  return f32 ? ((const float*)p)[i] : __bfloat162float(((const bf16*)p)[i]);
}

__device__ __forceinline__ long pack4(float a, float b, float c, float d) {
  union { bf16 h[4]; long l; } u;
  u.h[0] = f2b(a); u.h[1] = f2b(b); u.h[2] = f2b(c); u.h[3] = f2b(d);
  return u.l;
}
__device__ __forceinline__ void unpack4(long l, float* o) {
  union { bf16 h[4]; long l; } u; u.l = l;
  o[0] = b2f(u.h[0]); o[1] = b2f(u.h[1]); o[2] = b2f(u.h[2]); o[3] = b2f(u.h[3]);
}

__device__ __forceinline__ short8 ldfrag(const bf16* base, int row, int stride, int k0, int hl) {
  const bf16* p = base + (size_t)row * stride + k0 + (hl << 3);
  union { short8 v; long l[2]; } u;
  u.l[0] = *(const long*)p;
  u.l[1] = *(const long*)(p + 4);
  return u.v;
}

__device__ __forceinline__ f32x16 MFMA(short8 a, short8 b, f32x16 c) {
  return __builtin_amdgcn_mfma_f32_32x32x16_bf16(a, b, c, 0, 0, 0);
}

struct PtrArr { const void* p[36]; int n[36]; };

// ---------- dtype sniffer ----------
__global__ __launch_bounds__(256) void sniff_kern(PtrArr pa, int* __restrict__ flags) {
  int t = blockIdx.x;
  const bf16* x = (const bf16*)pa.p[t];
  int n = pa.n[t]; if (n > 4096) n = 4096;
  __shared__ int cnt;
  if (threadIdx.x == 0) cnt = 0;
  __syncthreads();
  int c = 0;
  for (int i = threadIdx.x; i < n; i += 256) {
    float v = fabsf(__bfloat162float(x[i]));
    if (v == 0.f || (v >= 1e-6f && v <= 1024.f)) c++;
  }
  atomicAdd(&cnt, c);
  __syncthreads();
  if (threadIdx.x == 0) flags[t] = (cnt >= (n * 7) / 8) ? 0 : 1;
}

// ---------- transpose (B,C,N) raw -> token-major (P, ldd) bf16 ----------
__global__ __launch_bounds__(256) void tr_in_kern(const void* __restrict__ src,
                                                  const int* __restrict__ flags, int fIdx,
                                                  bf16* __restrict__ dst,
                                                  int C, int ldd, int coff) {
  __shared__ float tile[64][65];
  const int f32 = flags[fIdx];
  int b = blockIdx.z, n0 = blockIdx.x * 64, c0 = blockIdx.y * 64;
  int tx = threadIdx.x & 63, ty = threadIdx.x >> 6;
  for (int r = ty; r < 64; r += 4)
    tile[r][tx] = ldany(src, (size_t)(b * C + c0 + r) * NN + n0 + tx, f32);
  __syncthreads();
  for (int r = ty; r < 64; r += 4)
    dst[(size_t)(b * NN + n0 + r) * ldd + coff + c0 + tx] = __float2bfloat16(tile[tx][r]);
}

// ---------- coords (B,dd,N) raw -> (P,4) fp32 ----------
__global__ __launch_bounds__(256) void tr_coords_kern(const void* __restrict__ src,
                                                      const int* __restrict__ flags, int fIdx,
                                                      float* __restrict__ dst, int dd) {
  const int f32 = flags[fIdx];
  int i = blockIdx.x * 256 + threadIdx.x;
  if (i >= PP * 4) return;
  int p = i >> 2, j = i & 3;
  int b = p >> 11, n = p & (NN - 1);
  dst[i] = (j < dd) ? ldany(src, (size_t)(b * dd + j) * NN + n, f32) : 0.f;
}

// ---------- token-major linear ----------
__global__ __launch_bounds__(256) void linear_kern(
    const bf16* __restrict__ X, int ldx, int Cin, int cinLog,
    const void* __restrict__ W, const void* __restrict__ bias,
    const int* __restrict__ flags, int wIdx, int bIdx,
    const bf16* __restrict__ add, bf16* __restrict__ out, int ldout, int relu) {
  __shared__ __attribute__((aligned(16))) float xt[16 * 256];
  __shared__ __attribute__((aligned(16))) float wbuf[64 * 132];
  const int wf = flags[wIdx], bfl = flags[bIdx];
  int tid = threadIdx.x;
  int p0 = blockIdx.x * 16, o0 = blockIdx.y * 64;
  for (int i = tid; i < 16 * Cin; i += 256) {
    int pl = i >> cinLog, c = i & (Cin - 1);
    xt[i] = b2f(X[(size_t)(p0 + pl) * ldx + c]);
  }
  int o = tid & 63, pg = tid >> 6;
  float bv = ldany(bias, o0 + o, bfl);
  float acc[4] = {bv, bv, bv, bv};
  for (int ch = 0; ch < Cin; ch += 128) {
    __syncthreads();
    for (int i = tid; i < 64 * 128; i += 256) {
      int r = i >> 7, c = i & 127;
      wbuf[r * 132 + c] = ldany(W, (size_t)(o0 + r) * Cin + ch + c, wf);
    }
    __syncthreads();
    for (int c = 0; c < 128; c += 4) {
      float4 w = *(const float4*)&wbuf[o * 132 + c];
#pragma unroll
      for (int j = 0; j < 4; ++j) {
        const float4 xv = *(const float4*)&xt[((pg + 4 * j) << cinLog) + ch + c];
        acc[j] += w.x * xv.x + w.y * xv.y + w.z * xv.z + w.w * xv.w;
      }
    }
  }
#pragma unroll
  for (int j = 0; j < 4; ++j) {
    int p = p0 + pg + 4 * j;
    float v = acc[j];
    if (add) v += b2f(add[(size_t)p * 128 + o0 + o]);
    if (relu) v = fmaxf(v, 0.f);
    out[(size_t)p * ldout + o0 + o] = __float2bfloat16(v);
  }
}

// ---------- kNN: one wave per point, register top-16 + wave merge ----------
__global__ __launch_bounds__(256) void knn_kern(const float* __restrict__ coordsT,
                                                int* __restrict__ idxout) {
  __shared__ __attribute__((aligned(16))) float4 cds[NN];
  int tid = threadIdx.x, lane = tid & 63, wv = tid >> 6;
  int p0 = blockIdx.x * 4, b = p0 >> 11;
  for (int j = tid; j < NN; j += 256)
    cds[j] = *(const float4*)&coordsT[((size_t)(b << 11) + j) * 4];
  __syncthreads();
  int p = p0 + wv, n = p & (NN - 1);
  float4 cc = cds[n];
  float sqi = __fadd_rn(__fadd_rn(__fmul_rn(cc.x, cc.x), __fmul_rn(cc.y, cc.y)),
                        __fmul_rn(cc.z, cc.z));
  ull t[16];
#pragma unroll
  for (int i = 0; i < 16; ++i) t[i] = ~0ull;
  for (int s = 0; s < 32; ++s) {
    int j = (s << 6) | lane;
    float4 q = cds[j];
    float sqj = __fadd_rn(__fadd_rn(__fmul_rn(q.x, q.x), __fmul_rn(q.y, q.y)),
                          __fmul_rn(q.z, q.z));
    float dt  = __fadd_rn(__fadd_rn(__fmul_rn(cc.x, q.x), __fmul_rn(cc.y, q.y)),
                          __fmul_rn(cc.z, q.z));
    float d2 = __fsub_rn(__fadd_rn(sqi, sqj), __fmul_rn(2.f, dt));
    unsigned u = __float_as_uint(d2);
    u = (u & 0x80000000u) ? ~u : (u | 0x80000000u);   // sortable ascending
    ull key = ((ull)u << 32) | (unsigned)j;
    if (key < t[15]) {
      t[15] = key;
#pragma unroll
      for (int i = 15; i > 0; --i) {
        ull lo = t[i - 1] < t[i] ? t[i - 1] : t[i];
        ull hi = t[i - 1] < t[i] ? t[i] : t[i - 1];
        t[i - 1] = lo; t[i] = hi;
      }
    }
  }
  // merge 64 sorted lists: 16 rounds of wave-min on heads
  for (int r = 0; r < KNB; ++r) {
    ull h = t[0];
    ull m = h;
#pragma unroll
    for (int off = 1; off < 64; off <<= 1) {
      ull o = __shfl_xor(m, off);
      m = o < m ? o : m;
    }
    if (lane == 0) idxout[(size_t)p * KNB + r] = (int)(m & 0xffffffffu);
    if (h == m) {   // unique keys -> exactly one owner pops its head
#pragma unroll
      for (int i = 0; i < 15; ++i) t[i] = t[i + 1];
      t[15] = ~0ull;
    }
  }
}

// ---------- weight-image prep: pad weights into image layout + fp32 biases ----------
__global__ __launch_bounds__(256) void prep_kern(
    const void* cw1, const void* cb1, const void* cw2, const void* cb2,
    const void* aw1, const void* ab1, const void* aw2, const void* ab2,
    const int* __restrict__ flags, int cIdx, int aIdx, int dd,
    bf16* __restrict__ w1img, bf16* __restrict__ w2img, bf16* __restrict__ cw2img,
    float* __restrict__ fb) {
  int i = blockIdx.x * 256 + threadIdx.x;
  const int fcw1 = flags[cIdx], fcb1 = flags[cIdx + 1];
  const int fcw2 = flags[cIdx + 2], fcb2 = flags[cIdx + 3];
  const int faw1 = flags[aIdx], fab1 = flags[aIdx + 1];
  const int faw2 = flags[aIdx + 2], fab2 = flags[aIdx + 3];
  float* ab1f = fb;          // 512
  float* ab2f = fb + 512;    // 128
  float* cb1f = fb + 640;    // 64
  float* cb2f = fb + 704;    // 128
  float* cw1f = fb + 832;    // 192
  if (i < 65536) {                       // w1img: [h_glob 512][132]
    int hg = i >> 7, c = i & 127;
    w1img[(size_t)hg * 132 + c] = f2b(ldany(aw1, i, faw1));
  } else if (i < 131072) {               // w2img: [ac*128+o][132] col=h_local
    int j = i - 65536;
    int o = j >> 9, hh = j & 511;
    int ac = hh >> 7, hloc = hh & 127;
    w2img[(size_t)(ac * 128 + o) * 132 + hloc] = f2b(ldany(aw2, j, faw2));
  } else if (i < 139264) {               // cw2img: [o 128][68]
    int j = i - 131072;
    int o = j >> 6, h = j & 63;
    cw2img[o * 68 + h] = f2b(ldany(cw2, j, fcw2));
  } else if (i < 139776) {
    int j = i - 139264; ab1f[j] = ldany(ab1, j, fab1);
  } else if (i < 139904) {
    int j = i - 139776; ab2f[j] = ldany(ab2, j, fab2);
  } else if (i < 139968) {
    int j = i - 139904; cb1f[j] = ldany(cb1, j, fcb1);
  } else if (i < 140096) {
    int j = i - 139968; cb2f[j] = ldany(cb2, j, fcb2);
  } else if (i < 140288) {
    int j = i - 140096;
    int h = j / 3, c = j % 3;
    cw1f[j] = (c < dd) ? ldany(cw1, h * dd + c, fcw1) : 0.f;
  }
}

// ---------- MFMA fused kNN attention: 8 points / 128 tokens per workgroup ----------
// LDS 72192 B -> 2 WG/CU; weights read straight from L2-hot global images.
#define SMEM_BYTES 72192
__global__ __launch_bounds__(512, 4) void attn_mfma(
    const bf16* __restrict__ centerT, const bf16* __restrict__ gatherT,
    const float* __restrict__ coordsT, const bf16* __restrict__ vfeatT,
    const int* __restrict__ idx,
    const bf16* __restrict__ w1img, const bf16* __restrict__ w2img,
    const bf16* __restrict__ cw2img, const float* __restrict__ fb,
    bf16* __restrict__ aggT) {
  extern __shared__ char smem[];
  bf16* XS  = (bf16*)(smem);            // [128][132]  x = kq_rel + emb
  bf16* HT  = (bf16*)(smem + 33792);    // [128][132]  hidden chunk [m][h]
  bf16* HC  = HT;                       // [128][68] coord hidden (aliases HT; dead before chunk 0)
  bf16* CFE = (bf16*)(smem + 67584);    // [8][128]
  bf16* VF  = (bf16*)(smem + 69632);    // [8][128]
  int*  NID = (int*)(smem + 71680);     // [128]
  const float* ab1f = fb;
  const float* ab2f = fb + 512;
  const float* cb1f = fb + 640;
  const float* cb2f = fb + 704;
  const float* cw1f = fb + 832;

  int tid = threadIdx.x, lane = tid & 63, wv = tid >> 6;
  int hl = lane >> 5, cA = lane & 31;
  int P0 = blockIdx.x * 8, b = P0 >> 11;

  // phase 0: stage NID/CFE/VF
  if (tid < 128) NID[tid] = (b << 11) + idx[(size_t)(P0 + (tid >> 4)) * KNB + (tid & 15)];
  for (int i = tid; i < 1024; i += 512) {
    int g = i >> 7, d = i & 127;
    CFE[i] = centerT[(size_t)(P0 + g) * 128 + d];
    VF[i]  = vfeatT[(size_t)(P0 + g) * 128 + d];
  }
  __syncthreads();

  // phase 1: coord hidden HC + XS base (= cfe - gathered)
  {
    int m = tid >> 2, sub = tid & 3;
    float4 ccd = *(const float4*)&coordsT[(size_t)(P0 + (m >> 4)) * 4];
    float4 nbd = *(const float4*)&coordsT[(size_t)NID[m] * 4];
    float r0 = ccd.x - nbd.x, r1 = ccd.y - nbd.y, r2 = ccd.z - nbd.z;
    int h0 = sub * 16;
    for (int hh = h0; hh < h0 + 16; hh += 4) {
      float a0 = fmaxf(cb1f[hh+0] + cw1f[(hh+0)*3]*r0 + cw1f[(hh+0)*3+1]*r1 + cw1f[(hh+0)*3+2]*r2, 0.f);
      float a1 = fmaxf(cb1f[hh+1] + cw1f[(hh+1)*3]*r0 + cw1f[(hh+1)*3+1]*r1 + cw1f[(hh+1)*3+2]*r2, 0.f);
      float a2 = fmaxf(cb1f[hh+2] + cw1f[(hh+2)*3]*r0 + cw1f[(hh+2)*3+1]*r1 + cw1f[(hh+2)*3+2]*r2, 0.f);
      float a3 = fmaxf(cb1f[hh+3] + cw1f[(hh+3)*3]*r0 + cw1f[(hh+3)*3+1]*r1 + cw1f[(hh+3)*3+2]*r2, 0.f);
      *(long*)&HC[m * 68 + hh] = pack4(a0, a1, a2, a3);
    }
    const bf16* grow = gatherT + (size_t)NID[m] * 128 + sub * 32;
    const bf16* crow = CFE + ((m >> 4) << 7) + sub * 32;
    for (int j = 0; j < 32; j += 4) {
      float gv[4], cv[4];
      unpack4(*(const long*)(grow + j), gv);
      unpack4(*(const long*)(crow + j), cv);
      *(long*)&XS[m * 132 + sub * 32 + j] =
          pack4(cv[0] - gv[0], cv[1] - gv[1], cv[2] - gv[2], cv[3] - gv[3]);
    }
  }
  __syncthreads();

  int r0s = (wv & 3) * 32;     // output-row strip (o / h)
  int mt0 = (wv >> 2) * 64;    // token strip (2 tiles of 32)

  // phase 2: emb GEMM (C_e[o][m] = cw2 @ HC + cb2), RMW into XS
  {
    f32x16 eacc[2];
#pragma unroll
    for (int r = 0; r < 16; ++r) {
      int o = r0s + (r & 3) + 8 * (r >> 2) + 4 * hl;
      float bv = cb2f[o];
      eacc[0][r] = bv; eacc[1][r] = bv;
    }
    for (int k0 = 0; k0 < 64; k0 += 16) {
      short8 af = ldfrag(cw2img, r0s + cA, 68, k0, hl);   // global, L2-hot
      short8 b0 = ldfrag(HC, mt0 + cA, 68, k0, hl);
      short8 b1 = ldfrag(HC, mt0 + 32 + cA, 68, k0, hl);
      eacc[0] = MFMA(af, b0, eacc[0]);
      eacc[1] = MFMA(af, b1, eacc[1]);
    }
#pragma unroll
    for (int t = 0; t < 2; ++t) {
      int m = mt0 + t * 32 + cA;
#pragma unroll
      for (int q = 0; q < 4; ++q) {
        int ob = r0s + 8 * q + 4 * hl;
        bf16* px = &XS[m * 132 + ob];
        float xv[4];
        unpack4(*(long*)px, xv);
        *(long*)px = pack4(xv[0] + eacc[t][4*q+0], xv[1] + eacc[t][4*q+1],
                           xv[2] + eacc[t][4*q+2], xv[3] + eacc[t][4*q+3]);
      }
    }
  }
  __syncthreads();

  // logits accumulator (bias-init)
  f32x16 acc2[2];
#pragma unroll
  for (int r = 0; r < 16; ++r) {
    int o = r0s + (r & 3) + 8 * (r >> 2) + 4 * hl;
    float bv = ab2f[o];
    acc2[0][r] = bv; acc2[1][r] = bv;
  }

  // chunk loop: 4 x 128 hidden; W fragments straight from global images
  for (int ac = 0; ac < 4; ++ac) {
    const bf16* w1c = w1img + (size_t)ac * 16896;
    const bf16* w2c = w2img + (size_t)ac * 16896;
    // GEMM1: H[h][m] = relu(W1 @ X + ab1)
    f32x16 acc1[2];
#pragma unroll
    for (int r = 0; r < 16; ++r) {
      int h = r0s + (r & 3) + 8 * (r >> 2) + 4 * hl;
      float bv = ab1f[ac * 128 + h];
      acc1[0][r] = bv; acc1[1][r] = bv;
    }
#pragma unroll
    for (int ks = 0; ks < 8; ++ks) {
      short8 af = ldfrag(w1c, r0s + cA, 132, ks * 16, hl);
      short8 b0 = ldfrag(XS, mt0 + cA, 132, ks * 16, hl);
      short8 b1 = ldfrag(XS, mt0 + 32 + cA, 132, ks * 16, hl);
      acc1[0] = MFMA(af, b0, acc1[0]);
      acc1[1] = MFMA(af, b1, acc1[1]);
    }
    __syncthreads();  // prior chunk's HT reads (and phase-2 HC reads) complete
#pragma unroll
    for (int t = 0; t < 2; ++t) {
      int m = mt0 + t * 32 + cA;
#pragma unroll
      for (int q = 0; q < 4; ++q) {
        int hb = r0s + 8 * q + 4 * hl;
        *(long*)&HT[m * 132 + hb] =
            pack4(fmaxf(acc1[t][4*q+0], 0.f), fmaxf(acc1[t][4*q+1], 0.f),
                  fmaxf(acc1[t][4*q+2], 0.f), fmaxf(acc1[t][4*q+3], 0.f));
      }
    }
    __syncthreads();  // HT complete
    // GEMM2: logits[o][m] += W2 @ H
#pragma unroll
    for (int ks = 0; ks < 8; ++ks) {
      short8 af = ldfrag(w2c, r0s + cA, 132, ks * 16, hl);
      short8 b0 = ldfrag(HT, mt0 + cA, 132, ks * 16, hl);
      short8 b1 = ldfrag(HT, mt0 + 32 + cA, 132, ks * 16, hl);
      acc2[0] = MFMA(af, b0, acc2[0]);
      acc2[1] = MFMA(af, b1, acc2[1]);
    }
  }

  // softmax-one over kk (16-lane groups) + aggregation
#pragma unroll
  for (int t = 0; t < 2; ++t) {
    int m = mt0 + t * 32 + cA;
    int g = m >> 4;
    float a[16];
#pragma unroll
    for (int r = 0; r < 16; ++r) {
      float x = acc2[t][r];
      float mx = x;
      mx = fmaxf(mx, __shfl_xor(mx, 1, 16));
      mx = fmaxf(mx, __shfl_xor(mx, 2, 16));
      mx = fmaxf(mx, __shfl_xor(mx, 4, 16));
      mx = fmaxf(mx, __shfl_xor(mx, 8, 16));
      float e = __expf(x - mx);
      float s = e;
      s += __shfl_xor(s, 1, 16);
      s += __shfl_xor(s, 2, 16);
      s += __shfl_xor(s, 4, 16);
      s += __shfl_xor(s, 8, 16);
      a[r] = e / (1.f + s);
    }
#pragma unroll
    for (int q = 0; q < 4; ++q) {
      int ob = r0s + 8 * q + 4 * hl;
      float xv[4], gv[4], vv[4], cv[4];
      unpack4(*(long*)&XS[m * 132 + ob], xv);
      unpack4(*(const long*)(gatherT + (size_t)NID[m] * 128 + ob), gv);
      unpack4(*(long*)&VF[(g << 7) + ob], vv);
      unpack4(*(long*)&CFE[(g << 7) + ob], cv);
      float p0 = a[4*q+0] * (vv[0] - cv[0] + xv[0] + gv[0]);
      float p1 = a[4*q+1] * (vv[1] - cv[1] + xv[1] + gv[1]);
      float p2 = a[4*q+2] * (vv[2] - cv[2] + xv[2] + gv[2]);
      float p3 = a[4*q+3] * (vv[3] - cv[3] + xv[3] + gv[3]);
#pragma unroll
      for (int s = 1; s < 16; s <<= 1) {
        p0 += __shfl_xor(p0, s, 16);
        p1 += __shfl_xor(p1, s, 16);
        p2 += __shfl_xor(p2, s, 16);
        p3 += __shfl_xor(p3, s, 16);
      }
      if ((lane & 15) == 0)
        *(long*)(aggT + (size_t)(P0 + g) * 128 + ob) = pack4(p0, p1, p2, p3);
    }
  }
}

// ---------- token-major bf16 (P,128) -> (B,128,N) output ----------
__global__ __launch_bounds__(256) void out_kern(const bf16* __restrict__ yT,
                                                void* __restrict__ outp,
                                                const int* __restrict__ flags, int ofIdx) {
  __shared__ float tile[64][65];
  const int f32 = flags[ofIdx];
  int b = blockIdx.z, n0 = blockIdx.x * 64, c0 = blockIdx.y * 64;
  int tx = threadIdx.x & 63, ty = threadIdx.x >> 6;
  for (int r = ty; r < 64; r += 4)
    tile[r][tx] = b2f(yT[(size_t)(b * NN + n0 + r) * 128 + c0 + tx]);
  __syncthreads();
  for (int r = ty; r < 64; r += 4) {
    size_t oi = (size_t)(b * CCH + c0 + r) * NN + n0 + tx;
    float v = tile[tx][r];
    if (f32) ((float*)outp)[oi] = v;
    else ((bf16*)outp)[oi] = __float2bfloat16(v);
  }
}

extern "C" void kernel_launch(void* const* d_in, const int* in_sizes, int n_in,
                              void* d_out, int out_size, void* d_ws, size_t ws_size,
                              hipStream_t stream) {
  const void* mv_w1 = d_in[4];  const void* mv_b1 = d_in[5];
  const void* mv_w2 = d_in[6];  const void* mv_b2 = d_in[7];
  const void* mv_ws = d_in[8];  const void* mv_bs = d_in[9];
  const void* wk    = d_in[10]; const void* bk    = d_in[11];
  const void* wq    = d_in[12]; const void* bq    = d_in[13];
  const void* wv    = d_in[14]; const void* bv    = d_in[15];
  const void* wkq   = d_in[32]; const void* bkq   = d_in[33];
  const void* wend  = d_in[34]; const void* bend  = d_in[35];

  // workspace layout
  int* flags = (int*)d_ws;
  bf16* catT = (bf16*)((float*)d_ws + 64);        // P x 256
  bf16* v0   = catT + (size_t)PP * 256;
  bf16* kT   = v0 + (size_t)PP * 128;
  bf16* qT   = kT + (size_t)PP * 128;
  bf16* sE   = qT + (size_t)PP * 128;             // vT, then value2
  bf16* sF   = sE + (size_t)PP * 128;             // tmp, agg1, agg2
  bf16* sG   = sF + (size_t)PP * 128;             // shortb, val1, yT
  float* xyzT = (float*)(sG + (size_t)PP * 128);  // P x 4
  float* posT = xyzT + (size_t)PP * 4;
  int* idxb = (int*)(posT + (size_t)PP * 4);      // P x 16
  bf16* w1i1 = (bf16*)(idxb + (size_t)PP * KNB);  // 4*128*132
  bf16* w2i1 = w1i1 + 67584;
  bf16* cw2i1 = w2i1 + 67584;                     // 128*68
  bf16* w1i2 = cw2i1 + 8704;
  bf16* w2i2 = w1i2 + 67584;
  bf16* cw2i2 = w2i2 + 67584;
  float* fb1 = (float*)(cw2i2 + 8704);            // 1024 floats
  float* fb2 = fb1 + 1024;

  PtrArr pa;
  for (int i = 0; i < 36; ++i) { pa.p[i] = d_in[i]; pa.n[i] = in_sizes[i]; }
  sniff_kern<<<dim3(36), 256, 0, stream>>>(pa, flags);

  prep_kern<<<dim3(548), 256, 0, stream>>>(d_in[16], d_in[17], d_in[18], d_in[19],
                                           d_in[24], d_in[25], d_in[26], d_in[27],
                                           flags, 16, 24, 3, w1i1, w2i1, cw2i1, fb1);
  prep_kern<<<dim3(548), 256, 0, stream>>>(d_in[20], d_in[21], d_in[22], d_in[23],
                                           d_in[28], d_in[29], d_in[30], d_in[31],
                                           flags, 20, 28, 2, w1i2, w2i2, cw2i2, fb2);

  dim3 trg(32, 2, 4);
  tr_in_kern<<<trg, 256, 0, stream>>>(d_in[2], flags, 2, catT, 128, 256, 0);
  tr_in_kern<<<trg, 256, 0, stream>>>(d_in[3], flags, 3, catT, 128, 256, 128);
  tr_coords_kern<<<dim3(128), 256, 0, stream>>>(d_in[0], flags, 0, xyzT, 3);
  tr_coords_kern<<<dim3(128), 256, 0, stream>>>(d_in[1], flags, 1, posT, 2);

  dim3 lg(PP / 16, 2);
  linear_kern<<<lg, 256, 0, stream>>>(catT, 256, 256, 8, mv_w1, mv_b1, flags, 4, 5, nullptr, sF, 128, 1);
  linear_kern<<<lg, 256, 0, stream>>>(catT, 256, 256, 8, mv_ws, mv_bs, flags, 8, 9, nullptr, sG, 128, 0);
  linear_kern<<<lg, 256, 0, stream>>>(sF,   128, 128, 7, mv_w2, mv_b2, flags, 6, 7, sG,      v0, 128, 0);
  linear_kern<<<lg, 256, 0, stream>>>(catT,       256, 128, 7, wk, bk, flags, 10, 11, nullptr, kT, 128, 0);
  linear_kern<<<lg, 256, 0, stream>>>(catT + 128, 256, 128, 7, wq, bq, flags, 12, 13, nullptr, qT, 128, 0);
  linear_kern<<<lg, 256, 0, stream>>>(v0,         128, 128, 7, wv, bv, flags, 14, 15, nullptr, sE, 128, 0);

  hipFuncSetAttribute((const void*)attn_mfma, hipFuncAttributeMaxDynamicSharedMemorySize, SMEM_BYTES);

  // block 1 (xyz): center=k, gathered=q, vfeat=v
  knn_kern<<<dim3(PP / 4), 256, 0, stream>>>(xyzT, idxb);
  attn_mfma<<<dim3(PP / 8), 512, SMEM_BYTES, stream>>>(kT, qT, xyzT, sE, idxb,
                                                       w1i1, w2i1, cw2i1, fb1, sF);
  linear_kern<<<lg, 256, 0, stream>>>(sF, 128, 128, 7, wkq, bkq, flags, 32, 33, v0, sG, 128, 0);
  linear_kern<<<lg, 256, 0, stream>>>(sG, 128, 128, 7, wv,  bv,  flags, 14, 15, nullptr, sE, 128, 0);
  // block 2 (pos): center=q, gathered=k, vfeat=value2
  knn_kern<<<dim3(PP / 4), 256, 0, stream>>>(posT, idxb);
  attn_mfma<<<dim3(PP / 8), 512, SMEM_BYTES, stream>>>(qT, kT, posT, sE, idxb,
                                                       w1i2, w2i2, cw2i2, fb2, sF);
  linear_kern<<<lg, 256, 0, stream>>>(sF, 128, 128, 7, wend, bend, flags, 34, 35, v0, sG, 128, 0);
  out_kern<<<trg, 256, 0, stream>>>(sG, d_out, flags, 2);
}

// Round 5
// 558.671 us; speedup vs baseline: 7.9115x; 1.3867x over previous
//
#include <hip/hip_runtime.h>
#include <hip/hip_bf16.h>

typedef __hip_bfloat16 bf16;
typedef unsigned long long ull;

#define BB 4
#define NN 2048
#define CCH 128
#define DDM 128
#define KNB 16
#define HHD 64
#define AAD 512
#define PP (BB*NN)

typedef __attribute__((ext_vector_type(8))) short short8;
typedef __attribute__((ext_vector_type(16))) float f32x16;

__device__ __forceinline__ float b2f(bf16 x) { return __bfloat162float(x); }
__device__ __forceinline__ bf16 f2b(float x) { return __float2bfloat16(x); }

__device__ __forceinline__ float ldany(const void* p, size_t i, int f32) {
  return f32 ? ((const float*)p)[i] : __bfloat162float(((const bf16*)p)[i]);
}

__device__ __forceinline__ long pack4(float a, float b, float c, float d) {
  union { bf16 h[4]; long l; } u;
  u.h[0] = f2b(a); u.h[1] = f2b(b); u.h[2] = f2b(c); u.h[3] = f2b(d);
  return u.l;
}
__device__ __forceinline__ void unpack4(long l, float* o) {
  union { bf16 h[4]; long l; } u; u.l = l;
  o[0] = b2f(u.h[0]); o[1] = b2f(u.h[1]); o[2] = b2f(u.h[2]); o[3] = b2f(u.h[3]);
}

__device__ __forceinline__ short8 ldfrag(const bf16* base, int row, int stride, int k0, int hl) {
  const bf16* p = base + (size_t)row * stride + k0 + (hl << 3);
  union { short8 v; long l[2]; } u;
  u.l[0] = *(const long*)p;
  u.l[1] = *(const long*)(p + 4);
  return u.v;
}

__device__ __forceinline__ f32x16 MFMA(short8 a, short8 b, f32x16 c) {
  return __builtin_amdgcn_mfma_f32_32x32x16_bf16(a, b, c, 0, 0, 0);
}

struct PtrArr { const void* p[36]; int n[36]; };
struct CvtTab { int src[16]; int off[16]; int n[16]; int isb[16]; };

// ---------- dtype sniffer ----------
__global__ __launch_bounds__(256) void sniff_kern(PtrArr pa, int* __restrict__ flags) {
  int t = blockIdx.x;
  const bf16* x = (const bf16*)pa.p[t];
  int n = pa.n[t]; if (n > 4096) n = 4096;
  __shared__ int cnt;
  if (threadIdx.x == 0) cnt = 0;
  __syncthreads();
  int c = 0;
  for (int i = threadIdx.x; i < n; i += 256) {
    float v = fabsf(__bfloat162float(x[i]));
    if (v == 0.f || (v >= 1e-6f && v <= 1024.f)) c++;
  }
  atomicAdd(&cnt, c);
  __syncthreads();
  if (threadIdx.x == 0) flags[t] = (cnt >= (n * 7) / 8) ? 0 : 1;
}

// ---------- convert GEMM weights/biases into bf16 arena + fp32 bias arena ----------
__global__ __launch_bounds__(256) void wcvt_kern(PtrArr pa, CvtTab tab,
                                                 const int* __restrict__ flags,
                                                 bf16* __restrict__ warena,
                                                 float* __restrict__ barena) {
  int e = blockIdx.y;
  int i = blockIdx.x * 256 + threadIdx.x;
  if (i >= tab.n[e]) return;
  float v = ldany(pa.p[tab.src[e]], i, flags[tab.src[e]]);
  if (tab.isb[e]) barena[tab.off[e] + i] = v;
  else warena[tab.off[e] + i] = f2b(v);
}

// ---------- transpose (B,C,N) raw -> token-major (P, ldd) bf16 ----------
__global__ __launch_bounds__(256) void tr_in_kern(const void* __restrict__ src,
                                                  const int* __restrict__ flags, int fIdx,
                                                  bf16* __restrict__ dst,
                                                  int C, int ldd, int coff) {
  __shared__ float tile[64][65];
  const int f32 = flags[fIdx];
  int b = blockIdx.z, n0 = blockIdx.x * 64, c0 = blockIdx.y * 64;
  int tx = threadIdx.x & 63, ty = threadIdx.x >> 6;
  for (int r = ty; r < 64; r += 4)
    tile[r][tx] = ldany(src, (size_t)(b * C + c0 + r) * NN + n0 + tx, f32);
  __syncthreads();
  for (int r = ty; r < 64; r += 4)
    dst[(size_t)(b * NN + n0 + r) * ldd + coff + c0 + tx] = __float2bfloat16(tile[tx][r]);
}

// ---------- coords (B,dd,N) raw -> (P,4) fp32 ----------
__global__ __launch_bounds__(256) void tr_coords_kern(const void* __restrict__ src,
                                                      const int* __restrict__ flags, int fIdx,
                                                      float* __restrict__ dst, int dd) {
  const int f32 = flags[fIdx];
  int i = blockIdx.x * 256 + threadIdx.x;
  if (i >= PP * 4) return;
  int p = i >> 2, j = i & 3;
  int b = p >> 11, n = p & (NN - 1);
  dst[i] = (j < dd) ? ldany(src, (size_t)(b * dd + j) * NN + n, f32) : 0.f;
}

// ---------- MFMA GEMM: out[p][o] = act(X[p]·W[o] + b[o] (+ add[p][o])) ----------
// 64 tokens x 128 outputs per WG; W read from L2-hot bf16 arena [128][K].
__global__ __launch_bounds__(256) void gemm_kern(
    const bf16* __restrict__ X, int ldx, int K,
    const bf16* __restrict__ Wb, const float* __restrict__ bias,
    const bf16* __restrict__ add, bf16* __restrict__ out, int relu) {
  __shared__ __attribute__((aligned(16))) bf16 XT[64 * 260];
  int tid = threadIdx.x, lane = tid & 63, wv = tid >> 6;
  int hl = lane >> 5, cA = lane & 31;
  int p0 = blockIdx.x * 64;
  int SK = K + 4;                       // (K+4)/2 mod 32 == 2 -> free 2-way only
  int kc = K >> 3;                      // 16B chunks per row
  for (int c = tid; c < 64 * kc; c += 256) {
    int r = c / kc, col = (c % kc) << 3;
    *(float4*)&XT[r * SK + col] = *(const float4*)&X[(size_t)(p0 + r) * ldx + col];
  }
  __syncthreads();
  int o0 = wv * 32;
  f32x16 acc[2];
#pragma unroll
  for (int r = 0; r < 16; ++r) {
    int o = o0 + (r & 3) + 8 * (r >> 2) + 4 * hl;
    float bv = bias[o];
    acc[0][r] = bv; acc[1][r] = bv;
  }
  for (int ks = 0; ks < (K >> 4); ++ks) {
    short8 af = ldfrag(Wb, o0 + cA, K, ks * 16, hl);
    short8 b0 = ldfrag(XT, cA, SK, ks * 16, hl);
    short8 b1 = ldfrag(XT, 32 + cA, SK, ks * 16, hl);
    acc[0] = MFMA(af, b0, acc[0]);
    acc[1] = MFMA(af, b1, acc[1]);
  }
#pragma unroll
  for (int t = 0; t < 2; ++t) {
    int m = p0 + t * 32 + cA;
#pragma unroll
    for (int q = 0; q < 4; ++q) {
      int ob = o0 + 8 * q + 4 * hl;
      float v[4] = {acc[t][4*q+0], acc[t][4*q+1], acc[t][4*q+2], acc[t][4*q+3]};
      if (add) {
        float av[4];
        unpack4(*(const long*)(add + (size_t)m * 128 + ob), av);
        v[0] += av[0]; v[1] += av[1]; v[2] += av[2]; v[3] += av[3];
      }
      if (relu) {
        v[0] = fmaxf(v[0], 0.f); v[1] = fmaxf(v[1], 0.f);
        v[2] = fmaxf(v[2], 0.f); v[3] = fmaxf(v[3], 0.f);
      }
      *(long*)(out + (size_t)m * 128 + ob) = pack4(v[0], v[1], v[2], v[3]);
    }
  }
}

// ---------- kNN: one wave per point, register top-16 + wave merge ----------
__global__ __launch_bounds__(256) void knn_kern(const float* __restrict__ coordsT,
                                                int* __restrict__ idxout) {
  __shared__ __attribute__((aligned(16))) float4 cds[NN];
  int tid = threadIdx.x, lane = tid & 63, wv = tid >> 6;
  int p0 = blockIdx.x * 4, b = p0 >> 11;
  for (int j = tid; j < NN; j += 256)
    cds[j] = *(const float4*)&coordsT[((size_t)(b << 11) + j) * 4];
  __syncthreads();
  int p = p0 + wv, n = p & (NN - 1);
  float4 cc = cds[n];
  float sqi = __fadd_rn(__fadd_rn(__fmul_rn(cc.x, cc.x), __fmul_rn(cc.y, cc.y)),
                        __fmul_rn(cc.z, cc.z));
  ull t[16];
#pragma unroll
  for (int i = 0; i < 16; ++i) t[i] = ~0ull;
  for (int s = 0; s < 32; ++s) {
    int j = (s << 6) | lane;
    float4 q = cds[j];
    float sqj = __fadd_rn(__fadd_rn(__fmul_rn(q.x, q.x), __fmul_rn(q.y, q.y)),
                          __fmul_rn(q.z, q.z));
    float dt  = __fadd_rn(__fadd_rn(__fmul_rn(cc.x, q.x), __fmul_rn(cc.y, q.y)),
                          __fmul_rn(cc.z, q.z));
    float d2 = __fsub_rn(__fadd_rn(sqi, sqj), __fmul_rn(2.f, dt));
    unsigned u = __float_as_uint(d2);
    u = (u & 0x80000000u) ? ~u : (u | 0x80000000u);   // sortable ascending
    ull key = ((ull)u << 32) | (unsigned)j;
    if (key < t[15]) {
      t[15] = key;
#pragma unroll
      for (int i = 15; i > 0; --i) {
        ull lo = t[i - 1] < t[i] ? t[i - 1] : t[i];
        ull hi = t[i - 1] < t[i] ? t[i] : t[i - 1];
        t[i - 1] = lo; t[i] = hi;
      }
    }
  }
  for (int r = 0; r < KNB; ++r) {
    ull h = t[0];
    ull m = h;
#pragma unroll
    for (int off = 1; off < 64; off <<= 1) {
      ull o = __shfl_xor(m, off);
      m = o < m ? o : m;
    }
    if (lane == 0) idxout[(size_t)p * KNB + r] = (int)(m & 0xffffffffu);
    if (h == m) {
#pragma unroll
      for (int i = 0; i < 15; ++i) t[i] = t[i + 1];
      t[15] = ~0ull;
    }
  }
}

// ---------- weight-image prep for attn ----------
__global__ __launch_bounds__(256) void prep_kern(
    const void* cw1, const void* cb1, const void* cw2, const void* cb2,
    const void* aw1, const void* ab1, const void* aw2, const void* ab2,
    const int* __restrict__ flags, int cIdx, int aIdx, int dd,
    bf16* __restrict__ w1img, bf16* __restrict__ w2img, bf16* __restrict__ cw2img,
    float* __restrict__ fb) {
  int i = blockIdx.x * 256 + threadIdx.x;
  const int fcw1 = flags[cIdx], fcb1 = flags[cIdx + 1];
  const int fcw2 = flags[cIdx + 2], fcb2 = flags[cIdx + 3];
  const int faw1 = flags[aIdx], fab1 = flags[aIdx + 1];
  const int faw2 = flags[aIdx + 2], fab2 = flags[aIdx + 3];
  float* ab1f = fb;          // 512
  float* ab2f = fb + 512;    // 128
  float* cb1f = fb + 640;    // 64
  float* cb2f = fb + 704;    // 128
  float* cw1f = fb + 832;    // 192
  if (i < 65536) {                       // w1img: [h_glob 512][132]
    int hg = i >> 7, c = i & 127;
    w1img[(size_t)hg * 132 + c] = f2b(ldany(aw1, i, faw1));
  } else if (i < 131072) {               // w2img: [ac*128+o][132] col=h_local
    int j = i - 65536;
    int o = j >> 9, hh = j & 511;
    int ac = hh >> 7, hloc = hh & 127;
    w2img[(size_t)(ac * 128 + o) * 132 + hloc] = f2b(ldany(aw2, j, faw2));
  } else if (i < 139264) {               // cw2img: [o 128][68]
    int j = i - 131072;
    int o = j >> 6, h = j & 63;
    cw2img[o * 68 + h] = f2b(ldany(cw2, j, fcw2));
  } else if (i < 139776) {
    int j = i - 139264; ab1f[j] = ldany(ab1, j, fab1);
  } else if (i < 139904) {
    int j = i - 139776; ab2f[j] = ldany(ab2, j, fab2);
  } else if (i < 139968) {
    int j = i - 139904; cb1f[j] = ldany(cb1, j, fcb1);
  } else if (i < 140096) {
    int j = i - 139968; cb2f[j] = ldany(cb2, j, fcb2);
  } else if (i < 140288) {
    int j = i - 140096;
    int h = j / 3, c = j % 3;
    cw1f[j] = (c < dd) ? ldany(cw1, h * dd + c, fcw1) : 0.f;
  }
}

// ---------- MFMA fused kNN attention: 8 points / 128 tokens per workgroup ----------
#define SMEM_BYTES 72192
__global__ __launch_bounds__(512, 4) void attn_mfma(
    const bf16* __restrict__ centerT, const bf16* __restrict__ gatherT,
    const float* __restrict__ coordsT, const bf16* __restrict__ vfeatT,
    const int* __restrict__ idx,
    const bf16* __restrict__ w1img, const bf16* __restrict__ w2img,
    const bf16* __restrict__ cw2img, const float* __restrict__ fb,
    bf16* __restrict__ aggT) {
  extern __shared__ char smem[];
  bf16* XS  = (bf16*)(smem);            // [128][132]
  bf16* HT  = (bf16*)(smem + 33792);    // [128][132]
  bf16* HC  = HT;                       // [128][68] aliases HT
  bf16* CFE = (bf16*)(smem + 67584);    // [8][128]
  bf16* VF  = (bf16*)(smem + 69632);    // [8][128]
  int*  NID = (int*)(smem + 71680);     // [128]
  const float* ab1f = fb;
  const float* ab2f = fb + 512;
  const float* cb1f = fb + 640;
  const float* cb2f = fb + 704;
  const float* cw1f = fb + 832;

  int tid = threadIdx.x, lane = tid & 63, wv = tid >> 6;
  int hl = lane >> 5, cA = lane & 31;
  int P0 = blockIdx.x * 8, b = P0 >> 11;

  if (tid < 128) NID[tid] = (b << 11) + idx[(size_t)(P0 + (tid >> 4)) * KNB + (tid & 15)];
  for (int i = tid; i < 1024; i += 512) {
    int g = i >> 7, d = i & 127;
    CFE[i] = centerT[(size_t)(P0 + g) * 128 + d];
    VF[i]  = vfeatT[(size_t)(P0 + g) * 128 + d];
  }
  __syncthreads();

  {
    int m = tid >> 2, sub = tid & 3;
    float4 ccd = *(const float4*)&coordsT[(size_t)(P0 + (m >> 4)) * 4];
    float4 nbd = *(const float4*)&coordsT[(size_t)NID[m] * 4];
    float r0 = ccd.x - nbd.x, r1 = ccd.y - nbd.y, r2 = ccd.z - nbd.z;
    int h0 = sub * 16;
    for (int hh = h0; hh < h0 + 16; hh += 4) {
      float a0 = fmaxf(cb1f[hh+0] + cw1f[(hh+0)*3]*r0 + cw1f[(hh+0)*3+1]*r1 + cw1f[(hh+0)*3+2]*r2, 0.f);
      float a1 = fmaxf(cb1f[hh+1] + cw1f[(hh+1)*3]*r0 + cw1f[(hh+1)*3+1]*r1 + cw1f[(hh+1)*3+2]*r2, 0.f);
      float a2 = fmaxf(cb1f[hh+2] + cw1f[(hh+2)*3]*r0 + cw1f[(hh+2)*3+1]*r1 + cw1f[(hh+2)*3+2]*r2, 0.f);
      float a3 = fmaxf(cb1f[hh+3] + cw1f[(hh+3)*3]*r0 + cw1f[(hh+3)*3+1]*r1 + cw1f[(hh+3)*3+2]*r2, 0.f);
      *(long*)&HC[m * 68 + hh] = pack4(a0, a1, a2, a3);
    }
    const bf16* grow = gatherT + (size_t)NID[m] * 128 + sub * 32;
    const bf16* crow = CFE + ((m >> 4) << 7) + sub * 32;
    for (int j = 0; j < 32; j += 4) {
      float gv[4], cv[4];
      unpack4(*(const long*)(grow + j), gv);
      unpack4(*(const long*)(crow + j), cv);
      *(long*)&XS[m * 132 + sub * 32 + j] =
          pack4(cv[0] - gv[0], cv[1] - gv[1], cv[2] - gv[2], cv[3] - gv[3]);
    }
  }
  __syncthreads();

  int r0s = (wv & 3) * 32;
  int mt0 = (wv >> 2) * 64;

  {
    f32x16 eacc[2];
#pragma unroll
    for (int r = 0; r < 16; ++r) {
      int o = r0s + (r & 3) + 8 * (r >> 2) + 4 * hl;
      float bv = cb2f[o];
      eacc[0][r] = bv; eacc[1][r] = bv;
    }
    for (int k0 = 0; k0 < 64; k0 += 16) {
      short8 af = ldfrag(cw2img, r0s + cA, 68, k0, hl);
      short8 b0 = ldfrag(HC, mt0 + cA, 68, k0, hl);
      short8 b1 = ldfrag(HC, mt0 + 32 + cA, 68, k0, hl);
      eacc[0] = MFMA(af, b0, eacc[0]);
      eacc[1] = MFMA(af, b1, eacc[1]);
    }
#pragma unroll
    for (int t = 0; t < 2; ++t) {
      int m = mt0 + t * 32 + cA;
#pragma unroll
      for (int q = 0; q < 4; ++q) {
        int ob = r0s + 8 * q + 4 * hl;
        bf16* px = &XS[m * 132 + ob];
        float xv[4];
        unpack4(*(long*)px, xv);
        *(long*)px = pack4(xv[0] + eacc[t][4*q+0], xv[1] + eacc[t][4*q+1],
                           xv[2] + eacc[t][4*q+2], xv[3] + eacc[t][4*q+3]);
      }
    }
  }
  __syncthreads();

  f32x16 acc2[2];
#pragma unroll
  for (int r = 0; r < 16; ++r) {
    int o = r0s + (r & 3) + 8 * (r >> 2) + 4 * hl;
    float bv = ab2f[o];
    acc2[0][r] = bv; acc2[1][r] = bv;
  }

  for (int ac = 0; ac < 4; ++ac) {
    const bf16* w1c = w1img + (size_t)ac * 16896;
    const bf16* w2c = w2img + (size_t)ac * 16896;
    f32x16 acc1[2];
#pragma unroll
    for (int r = 0; r < 16; ++r) {
      int h = r0s + (r & 3) + 8 * (r >> 2) + 4 * hl;
      float bv = ab1f[ac * 128 + h];
      acc1[0][r] = bv; acc1[1][r] = bv;
    }
#pragma unroll
    for (int ks = 0; ks < 8; ++ks) {
      short8 af = ldfrag(w1c, r0s + cA, 132, ks * 16, hl);
      short8 b0 = ldfrag(XS, mt0 + cA, 132, ks * 16, hl);
      short8 b1 = ldfrag(XS, mt0 + 32 + cA, 132, ks * 16, hl);
      acc1[0] = MFMA(af, b0, acc1[0]);
      acc1[1] = MFMA(af, b1, acc1[1]);
    }
    __syncthreads();
#pragma unroll
    for (int t = 0; t < 2; ++t) {
      int m = mt0 + t * 32 + cA;
#pragma unroll
      for (int q = 0; q < 4; ++q) {
        int hb = r0s + 8 * q + 4 * hl;
        *(long*)&HT[m * 132 + hb] =
            pack4(fmaxf(acc1[t][4*q+0], 0.f), fmaxf(acc1[t][4*q+1], 0.f),
                  fmaxf(acc1[t][4*q+2], 0.f), fmaxf(acc1[t][4*q+3], 0.f));
      }
    }
    __syncthreads();
#pragma unroll
    for (int ks = 0; ks < 8; ++ks) {
      short8 af = ldfrag(w2c, r0s + cA, 132, ks * 16, hl);
      short8 b0 = ldfrag(HT, mt0 + cA, 132, ks * 16, hl);
      short8 b1 = ldfrag(HT, mt0 + 32 + cA, 132, ks * 16, hl);
      acc2[0] = MFMA(af, b0, acc2[0]);
      acc2[1] = MFMA(af, b1, acc2[1]);
    }
  }

#pragma unroll
  for (int t = 0; t < 2; ++t) {
    int m = mt0 + t * 32 + cA;
    int g = m >> 4;
    float a[16];
#pragma unroll
    for (int r = 0; r < 16; ++r) {
      float x = acc2[t][r];
      float mx = x;
      mx = fmaxf(mx, __shfl_xor(mx, 1, 16));
      mx = fmaxf(mx, __shfl_xor(mx, 2, 16));
      mx = fmaxf(mx, __shfl_xor(mx, 4, 16));
      mx = fmaxf(mx, __shfl_xor(mx, 8, 16));
      float e = __expf(x - mx);
      float s = e;
      s += __shfl_xor(s, 1, 16);
      s += __shfl_xor(s, 2, 16);
      s += __shfl_xor(s, 4, 16);
      s += __shfl_xor(s, 8, 16);
      a[r] = e / (1.f + s);
    }
#pragma unroll
    for (int q = 0; q < 4; ++q) {
      int ob = r0s + 8 * q + 4 * hl;
      float xv[4], gv[4], vv[4], cv[4];
      unpack4(*(long*)&XS[m * 132 + ob], xv);
      unpack4(*(const long*)(gatherT + (size_t)NID[m] * 128 + ob), gv);
      unpack4(*(long*)&VF[(g << 7) + ob], vv);
      unpack4(*(long*)&CFE[(g << 7) + ob], cv);
      float p0 = a[4*q+0] * (vv[0] - cv[0] + xv[0] + gv[0]);
      float p1 = a[4*q+1] * (vv[1] - cv[1] + xv[1] + gv[1]);
      float p2 = a[4*q+2] * (vv[2] - cv[2] + xv[2] + gv[2]);
      float p3 = a[4*q+3] * (vv[3] - cv[3] + xv[3] + gv[3]);
#pragma unroll
      for (int s = 1; s < 16; s <<= 1) {
        p0 += __shfl_xor(p0, s, 16);
        p1 += __shfl_xor(p1, s, 16);
        p2 += __shfl_xor(p2, s, 16);
        p3 += __shfl_xor(p3, s, 16);
      }
      if ((lane & 15) == 0)
        *(long*)(aggT + (size_t)(P0 + g) * 128 + ob) = pack4(p0, p1, p2, p3);
    }
  }
}

// ---------- token-major bf16 (P,128) -> (B,128,N) output ----------
__global__ __launch_bounds__(256) void out_kern(const bf16* __restrict__ yT,
                                                void* __restrict__ outp,
                                                const int* __restrict__ flags, int ofIdx) {
  __shared__ float tile[64][65];
  const int f32 = flags[ofIdx];
  int b = blockIdx.z, n0 = blockIdx.x * 64, c0 = blockIdx.y * 64;
  int tx = threadIdx.x & 63, ty = threadIdx.x >> 6;
  for (int r = ty; r < 64; r += 4)
    tile[r][tx] = b2f(yT[(size_t)(b * NN + n0 + r) * 128 + c0 + tx]);
  __syncthreads();
  for (int r = ty; r < 64; r += 4) {
    size_t oi = (size_t)(b * CCH + c0 + r) * NN + n0 + tx;
    float v = tile[tx][r];
    if (f32) ((float*)outp)[oi] = v;
    else ((bf16*)outp)[oi] = __float2bfloat16(v);
  }
}

extern "C" void kernel_launch(void* const* d_in, const int* in_sizes, int n_in,
                              void* d_out, int out_size, void* d_ws, size_t ws_size,
                              hipStream_t stream) {
  // workspace layout
  int* flags = (int*)d_ws;
  bf16* catT = (bf16*)((float*)d_ws + 64);        // P x 256
  bf16* v0   = catT + (size_t)PP * 256;
  bf16* kT   = v0 + (size_t)PP * 128;
  bf16* qT   = kT + (size_t)PP * 128;
  bf16* sE   = qT + (size_t)PP * 128;             // vT, then value2
  bf16* sF   = sE + (size_t)PP * 128;             // tmp, agg1, agg2
  bf16* sG   = sF + (size_t)PP * 128;             // shortb, val1, yT
  float* xyzT = (float*)(sG + (size_t)PP * 128);  // P x 4
  float* posT = xyzT + (size_t)PP * 4;
  int* idxb = (int*)(posT + (size_t)PP * 4);      // P x 16
  bf16* w1i1 = (bf16*)(idxb + (size_t)PP * KNB);  // 4*128*132
  bf16* w2i1 = w1i1 + 67584;
  bf16* cw2i1 = w2i1 + 67584;                     // 128*68
  bf16* w1i2 = cw2i1 + 8704;
  bf16* w2i2 = w1i2 + 67584;
  bf16* cw2i2 = w2i2 + 67584;
  float* fb1 = (float*)(cw2i2 + 8704);            // 1024 floats
  float* fb2 = fb1 + 1024;
  bf16* warena = (bf16*)(fb2 + 1024);             // 163840 bf16
  float* barena = (float*)(warena + 163840);      // 1024 fp32

  PtrArr pa;
  for (int i = 0; i < 36; ++i) { pa.p[i] = d_in[i]; pa.n[i] = in_sizes[i]; }
  sniff_kern<<<dim3(36), 256, 0, stream>>>(pa, flags);

  // GEMM weight/bias arena offsets (elements)
  // weights: mv_w1 0, mv_ws 32768, mv_w2 65536, wk 81920, wq 98304, wv 114688,
  //          wkq 131072, wend 147456
  // biases:  mv_b1 0, mv_bs 128, mv_b2 256, bk 384, bq 512, bv 640, bkq 768, bend 896
  CvtTab tab;
  int wsrc[8] = {4, 8, 6, 10, 12, 14, 32, 34};
  int woff[8] = {0, 32768, 65536, 81920, 98304, 114688, 131072, 147456};
  int wn[8]   = {32768, 32768, 16384, 16384, 16384, 16384, 16384, 16384};
  int bsrc[8] = {5, 9, 7, 11, 13, 15, 33, 35};
  for (int e = 0; e < 8; ++e) {
    tab.src[e] = wsrc[e]; tab.off[e] = woff[e]; tab.n[e] = wn[e]; tab.isb[e] = 0;
    tab.src[8 + e] = bsrc[e]; tab.off[8 + e] = e * 128; tab.n[8 + e] = 128; tab.isb[8 + e] = 1;
  }
  wcvt_kern<<<dim3(128, 16), 256, 0, stream>>>(pa, tab, flags, warena, barena);

  prep_kern<<<dim3(548), 256, 0, stream>>>(d_in[16], d_in[17], d_in[18], d_in[19],
                                           d_in[24], d_in[25], d_in[26], d_in[27],
                                           flags, 16, 24, 3, w1i1, w2i1, cw2i1, fb1);
  prep_kern<<<dim3(548), 256, 0, stream>>>(d_in[20], d_in[21], d_in[22], d_in[23],
                                           d_in[28], d_in[29], d_in[30], d_in[31],
                                           flags, 20, 28, 2, w1i2, w2i2, cw2i2, fb2);

  dim3 trg(32, 2, 4);
  tr_in_kern<<<trg, 256, 0, stream>>>(d_in[2], flags, 2, catT, 128, 256, 0);
  tr_in_kern<<<trg, 256, 0, stream>>>(d_in[3], flags, 3, catT, 128, 256, 128);
  tr_coords_kern<<<dim3(128), 256, 0, stream>>>(d_in[0], flags, 0, xyzT, 3);
  tr_coords_kern<<<dim3(128), 256, 0, stream>>>(d_in[1], flags, 1, posT, 2);

  dim3 gg(PP / 64);
  // MLP_Res frontend
  gemm_kern<<<gg, 256, 0, stream>>>(catT, 256, 256, warena + 0,      barena + 0,   nullptr, sF, 1);
  gemm_kern<<<gg, 256, 0, stream>>>(catT, 256, 256, warena + 32768,  barena + 128, nullptr, sG, 0);
  gemm_kern<<<gg, 256, 0, stream>>>(sF,   128, 128, warena + 65536,  barena + 256, sG,      v0, 0);
  // k, q, v
  gemm_kern<<<gg, 256, 0, stream>>>(catT,       256, 128, warena + 81920,  barena + 384, nullptr, kT, 0);
  gemm_kern<<<gg, 256, 0, stream>>>(catT + 128, 256, 128, warena + 98304,  barena + 512, nullptr, qT, 0);
  gemm_kern<<<gg, 256, 0, stream>>>(v0,         128, 128, warena + 114688, barena + 640, nullptr, sE, 0);

  hipFuncSetAttribute((const void*)attn_mfma, hipFuncAttributeMaxDynamicSharedMemorySize, SMEM_BYTES);

  // block 1 (xyz): center=k, gathered=q, vfeat=v
  knn_kern<<<dim3(PP / 4), 256, 0, stream>>>(xyzT, idxb);
  attn_mfma<<<dim3(PP / 8), 512, SMEM_BYTES, stream>>>(kT, qT, xyzT, sE, idxb,
                                                       w1i1, w2i1, cw2i1, fb1, sF);
  gemm_kern<<<gg, 256, 0, stream>>>(sF, 128, 128, warena + 131072, barena + 768, v0, sG, 0);
  gemm_kern<<<gg, 256, 0, stream>>>(sG, 128, 128, warena + 114688, barena + 640, nullptr, sE, 0);
  // block 2 (pos): center=q, gathered=k, vfeat=value2
  knn_kern<<<dim3(PP / 4), 256, 0, stream>>>(posT, idxb);
  attn_mfma<<<dim3(PP / 8), 512, SMEM_BYTES, stream>>>(qT, kT, posT, sE, idxb,
                                                       w1i2, w2i2, cw2i2, fb2, sF);
  gemm_kern<<<gg, 256, 0, stream>>>(sF, 128, 128, warena + 147456, barena + 896, v0, sG, 0);
  out_kern<<<trg, 256, 0, stream>>>(sG, d_out, flags, 2);
}